// Round 1
// baseline (5140.118 us; speedup 1.0000x reference)
//
#include <hip/hip_runtime.h>
#include <hip/hip_bf16.h>

#define N_NODES 100000
#define N_EDGES 1600000
#define IN_DIM  128
#define HID     64
#define N_GRAPHS 500

// ---------- helpers ----------
__device__ inline unsigned fenc(float f) {
    unsigned u = __float_as_uint(f);
    return (u & 0x80000000u) ? ~u : (u | 0x80000000u);
}
__device__ inline float fdec(unsigned e) {
    unsigned u = (e & 0x80000000u) ? (e & 0x7FFFFFFFu) : ~e;
    return __uint_as_float(u);
}

// ---------- fused 4-way linear: q,k,v = x@W+b ; s (skip) -> hout ----------
// block: 256 threads, 16 rows per block. 4 rows per thread-group-of-64.
__global__ void fused_qkvs(const float* __restrict__ x, int N, int Din,
                           const float* __restrict__ Wq, const float* __restrict__ bq,
                           const float* __restrict__ Wk, const float* __restrict__ bk,
                           const float* __restrict__ Wv, const float* __restrict__ bv,
                           const float* __restrict__ Ws, const float* __restrict__ bs,
                           float* __restrict__ q, float* __restrict__ k,
                           float* __restrict__ v, float* __restrict__ hout)
{
    __shared__ float xs[16][IN_DIM];
    const int row0 = blockIdx.x * 16;
    const int tid  = threadIdx.x;

    for (int idx = tid; idx < 16 * Din; idx += 256) {
        int r = idx / Din, c = idx - r * Din;
        int gr = row0 + r;
        xs[r][c] = (gr < N) ? x[gr * Din + c] : 0.f;
    }
    __syncthreads();

    const int col  = tid & 63;
    const int rgrp = tid >> 6;   // 0..3 -> rows rgrp*4 .. rgrp*4+3

    float aq[4] = {0,0,0,0}, ak[4] = {0,0,0,0}, av[4] = {0,0,0,0}, as_[4] = {0,0,0,0};
    for (int kk = 0; kk < Din; ++kk) {
        float wq = Wq[kk * 64 + col];
        float wk = Wk[kk * 64 + col];
        float wv = Wv[kk * 64 + col];
        float ws = Ws[kk * 64 + col];
        #pragma unroll
        for (int e = 0; e < 4; ++e) {
            float xv = xs[rgrp * 4 + e][kk];   // broadcast (same addr across wave)
            aq[e] = fmaf(xv, wq, aq[e]);
            ak[e] = fmaf(xv, wk, ak[e]);
            av[e] = fmaf(xv, wv, av[e]);
            as_[e] = fmaf(xv, ws, as_[e]);
        }
    }
    #pragma unroll
    for (int e = 0; e < 4; ++e) {
        int row = row0 + rgrp * 4 + e;
        if (row < N) {
            q[row * 64 + col]    = aq[e] + bq[col];
            k[row * 64 + col]    = ak[e] + bk[col];
            v[row * 64 + col]    = av[e] + bv[col];
            hout[row * 64 + col] = as_[e] + bs[col];   // skip path; agg is atomically added later
        }
    }
}

// ---------- per-layer init: denom=0, mEnc=0 (enc(any finite) > 0) ----------
__global__ void init_nd(float* denom, unsigned* mEnc, int n) {
    int i = blockIdx.x * blockDim.x + threadIdx.x;
    if (i < n) { denom[i] = 0.f; mEnc[i] = 0u; }
}

__global__ void zero_f(float* p, int n) {
    int i = blockIdx.x * blockDim.x + threadIdx.x;
    if (i < n) p[i] = 0.f;
}

// ---------- edge scores + segment max (16 lanes per edge) ----------
__global__ void edge_scores(const float* __restrict__ q, const float* __restrict__ k,
                            const int* __restrict__ src, const int* __restrict__ dst,
                            float* __restrict__ scores, unsigned* __restrict__ mEnc, int E)
{
    int idx  = blockIdx.x * blockDim.x + threadIdx.x;
    int e    = idx >> 4;
    int lane = idx & 15;
    if (e >= E) return;
    int s = src[e], d = dst[e];
    float4 qv = ((const float4*)(q + (size_t)d * 64))[lane];
    float4 kv = ((const float4*)(k + (size_t)s * 64))[lane];
    float acc = qv.x * kv.x + qv.y * kv.y + qv.z * kv.z + qv.w * kv.w;
    acc += __shfl_xor(acc, 1);
    acc += __shfl_xor(acc, 2);
    acc += __shfl_xor(acc, 4);
    acc += __shfl_xor(acc, 8);
    if (lane == 0) {
        float sc = acc * 0.125f;   // / sqrt(64)
        scores[e] = sc;
        atomicMax(&mEnc[d], fenc(sc));
    }
}

// ---------- exp(score - m[dst]) + denom accumulation ----------
__global__ void edge_exp(float* __restrict__ scores, const int* __restrict__ dst,
                         const unsigned* __restrict__ mEnc, float* __restrict__ denom, int E)
{
    int e = blockIdx.x * blockDim.x + threadIdx.x;
    if (e >= E) return;
    int d = dst[e];
    float m  = fdec(mEnc[d]);
    float ex = expf(scores[e] - m);
    scores[e] = ex;
    atomicAdd(&denom[d], ex);
}

// ---------- aggregation: hout[dst] += alpha * v[src] ----------
__global__ void edge_agg(const float* __restrict__ v, const float* __restrict__ scores,
                         const float* __restrict__ denom,
                         const int* __restrict__ src, const int* __restrict__ dst,
                         float* __restrict__ hout, int E)
{
    int idx  = blockIdx.x * blockDim.x + threadIdx.x;
    int e    = idx >> 4;
    int lane = idx & 15;
    if (e >= E) return;
    int s = src[e], d = dst[e];
    float alpha = scores[e] / (denom[d] + 1e-16f);
    float4 vv = ((const float4*)(v + (size_t)s * 64))[lane];
    float* o = hout + (size_t)d * 64 + lane * 4;
    atomicAdd(o + 0, alpha * vv.x);
    atomicAdd(o + 1, alpha * vv.y);
    atomicAdd(o + 2, alpha * vv.z);
    atomicAdd(o + 3, alpha * vv.w);
}

__global__ void relu_kernel(float* p, int n) {
    int i = blockIdx.x * blockDim.x + threadIdx.x;
    if (i < n) p[i] = fmaxf(p[i], 0.f);
}

// ---------- pool: batch is sorted -> run-length accumulate, few atomics ----------
__global__ void pool_kernel(const float* __restrict__ h, const int* __restrict__ batch,
                            float* __restrict__ pooled, int N)
{
    int col  = threadIdx.x;           // 64 threads
    int base = blockIdx.x * 512;
    int end  = base + 512; if (end > N) end = N;
    int gcur = -1; float acc = 0.f;
    for (int i = base; i < end; ++i) {
        int g = batch[i];
        if (g != gcur) {
            if (gcur >= 0) atomicAdd(&pooled[gcur * 64 + col], acc);
            gcur = g; acc = 0.f;
        }
        acc += h[(size_t)i * 64 + col];
    }
    if (gcur >= 0) atomicAdd(&pooled[gcur * 64 + col], acc);
}

// ---------- MLP ----------
__global__ void mlp1(const float* __restrict__ pooled, const float* __restrict__ W1,
                     const float* __restrict__ b1, float* __restrict__ hidden)
{
    int idx = blockIdx.x * blockDim.x + threadIdx.x;
    if (idx >= N_GRAPHS * 64) return;
    int g = idx >> 6, c = idx & 63;
    float acc = b1[c];
    for (int kk = 0; kk < 64; ++kk)
        acc = fmaf(pooled[g * 64 + kk], W1[kk * 64 + c], acc);
    hidden[idx] = fmaxf(acc, 0.f);
}

__global__ void mlp2(const float* __restrict__ hidden, const float* __restrict__ W2,
                     const float* __restrict__ b2, float* __restrict__ out)
{
    int idx = blockIdx.x * blockDim.x + threadIdx.x;
    if (idx >= N_GRAPHS * 16) return;
    int g = idx >> 4, c = idx & 15;
    float acc = b2[c];
    for (int kk = 0; kk < 64; ++kk)
        acc = fmaf(hidden[g * 64 + kk], W2[kk * 16 + c], acc);
    out[idx] = acc;
}

extern "C" void kernel_launch(void* const* d_in, const int* in_sizes, int n_in,
                              void* d_out, int out_size, void* d_ws, size_t ws_size,
                              hipStream_t stream)
{
    const float* x   = (const float*)d_in[0];
    const float* Wq0 = (const float*)d_in[1];  const float* bq0 = (const float*)d_in[2];
    const float* Wk0 = (const float*)d_in[3];  const float* bk0 = (const float*)d_in[4];
    const float* Wv0 = (const float*)d_in[5];  const float* bv0 = (const float*)d_in[6];
    const float* Ws0 = (const float*)d_in[7];  const float* bs0 = (const float*)d_in[8];
    const float* Wqs = (const float*)d_in[9];  const float* bqs = (const float*)d_in[10];
    const float* Wks = (const float*)d_in[11]; const float* bks = (const float*)d_in[12];
    const float* Wvs = (const float*)d_in[13]; const float* bvs = (const float*)d_in[14];
    const float* Wss = (const float*)d_in[15]; const float* bss = (const float*)d_in[16];
    const float* W1  = (const float*)d_in[17]; const float* b1  = (const float*)d_in[18];
    const float* W2  = (const float*)d_in[19]; const float* b2  = (const float*)d_in[20];
    const int*   ei  = (const int*)d_in[21];
    const int*   batch = (const int*)d_in[22];
    float* out = (float*)d_out;

    const int* src = ei;
    const int* dst = ei + N_EDGES;

    const size_t NH = (size_t)N_NODES * 64;
    float* q      = (float*)d_ws;
    float* k      = q + NH;
    float* v      = k + NH;
    float* hA     = v + NH;
    float* hB     = hA + NH;
    float* scores = hB + NH;
    float* denom  = scores + N_EDGES;
    unsigned* mEnc = (unsigned*)(denom + N_NODES);
    float* pooled = denom + 2 * (size_t)N_NODES;
    float* hidden = pooled + N_GRAPHS * 64;

    struct LW { const float *Wq,*bq,*Wk,*bk,*Wv,*bv,*Ws,*bs; };
    LW lw[3] = {
        { Wq0, bq0, Wk0, bk0, Wv0, bv0, Ws0, bs0 },
        { Wqs, bqs, Wks, bks, Wvs, bvs, Wss, bss },
        { Wqs + 4096, bqs + 64, Wks + 4096, bks + 64, Wvs + 4096, bvs + 64, Wss + 4096, bss + 64 }
    };
    const float* lin_in[3] = { x, hA, hB };
    int          lin_dim[3] = { IN_DIM, HID, HID };
    float*       lin_out[3] = { hA, hB, hA };

    const int linBlocks  = (N_NODES + 15) / 16;
    const int edgeBlocks16 = (N_EDGES * 16 + 255) / 256;
    const int edgeBlocks   = (N_EDGES + 255) / 256;
    const int nodeBlocks   = (N_NODES + 255) / 256;
    const int featBlocks   = ((int)NH + 255) / 256;

    for (int L = 0; L < 3; ++L) {
        fused_qkvs<<<linBlocks, 256, 0, stream>>>(lin_in[L], N_NODES, lin_dim[L],
            lw[L].Wq, lw[L].bq, lw[L].Wk, lw[L].bk, lw[L].Wv, lw[L].bv, lw[L].Ws, lw[L].bs,
            q, k, v, lin_out[L]);
        init_nd<<<nodeBlocks, 256, 0, stream>>>(denom, mEnc, N_NODES);
        edge_scores<<<edgeBlocks16, 256, 0, stream>>>(q, k, src, dst, scores, mEnc, N_EDGES);
        edge_exp<<<edgeBlocks, 256, 0, stream>>>(scores, dst, mEnc, denom, N_EDGES);
        edge_agg<<<edgeBlocks16, 256, 0, stream>>>(v, scores, denom, src, dst, lin_out[L], N_EDGES);
        relu_kernel<<<featBlocks, 256, 0, stream>>>(lin_out[L], (int)NH);
    }

    zero_f<<<(N_GRAPHS * 64 + 255) / 256, 256, 0, stream>>>(pooled, N_GRAPHS * 64);
    pool_kernel<<<(N_NODES + 511) / 512, 64, 0, stream>>>(hA, batch, pooled, N_NODES);
    mlp1<<<(N_GRAPHS * 64 + 255) / 256, 256, 0, stream>>>(pooled, W1, b1, hidden);
    mlp2<<<(N_GRAPHS * 16 + 255) / 256, 256, 0, stream>>>(hidden, W2, b2, out);
}

// Round 4
// 1498.571 us; speedup vs baseline: 3.4300x; 3.4300x over previous
//
#include <hip/hip_runtime.h>
#include <hip/hip_bf16.h>

#define N_NODES 100000
#define N_EDGES 1600000
#define IN_DIM  128
#define HID     64
#define N_GRAPHS 500

// ============ CSR build ============
__global__ void zero_i(int* p, int n) {
    int i = blockIdx.x * blockDim.x + threadIdx.x;
    if (i < n) p[i] = 0;
}

__global__ void count_deg(const int* __restrict__ dst, int* __restrict__ counts, int E) {
    int e = blockIdx.x * blockDim.x + threadIdx.x;
    if (e < E) atomicAdd(&counts[dst[e]], 1);
}

// per-block exclusive scan of 256 elements + block total
__global__ void scan1(const int* __restrict__ counts, int* __restrict__ pre,
                      int* __restrict__ blockSums, int n) {
    __shared__ int tmp[256];
    int tid = threadIdx.x;
    int i = blockIdx.x * 256 + tid;
    int v = (i < n) ? counts[i] : 0;
    tmp[tid] = v; __syncthreads();
    int acc = v;
    for (int off = 1; off < 256; off <<= 1) {
        int add = (tid >= off) ? tmp[tid - off] : 0;
        __syncthreads();
        acc += add; tmp[tid] = acc;
        __syncthreads();
    }
    if (i < n) pre[i] = acc - v;                 // exclusive within block
    if (tid == 255) blockSums[blockIdx.x] = acc; // block total
}

// exclusive scan of <=512 block sums, in place (single block of 512)
__global__ void scan2(int* blockSums, int nb) {
    __shared__ int tmp[512];
    int tid = threadIdx.x;
    int v = (tid < nb) ? blockSums[tid] : 0;
    tmp[tid] = v; __syncthreads();
    int acc = v;
    for (int off = 1; off < 512; off <<= 1) {
        int add = (tid >= off) ? tmp[tid - off] : 0;
        __syncthreads();
        acc += add; tmp[tid] = acc;
        __syncthreads();
    }
    if (tid < nb) blockSums[tid] = acc - v;
}

// row_start[i] = pre[i] + blockSums[i/256]; row_start[n] = E; cursor = row_start
__global__ void scan3(const int* __restrict__ pre, const int* __restrict__ blockSums,
                      int* __restrict__ row_start, int* __restrict__ cursor, int n, int E) {
    int i = blockIdx.x * blockDim.x + threadIdx.x;
    if (i < n) {
        int r = pre[i] + blockSums[i >> 8];
        row_start[i] = r;
        cursor[i] = r;
    } else if (i == n) {
        row_start[n] = E;
    }
}

// slot[e] = position of edge e in CSR order; csr_src[slot] = src[e]
__global__ void csr_fill(const int* __restrict__ src, const int* __restrict__ dst,
                         int* __restrict__ cursor, int* __restrict__ slot,
                         int* __restrict__ csr_src, int E) {
    int e = blockIdx.x * blockDim.x + threadIdx.x;
    if (e >= E) return;
    int d = dst[e];
    int p = atomicAdd(&cursor[d], 1);
    slot[e] = p;
    csr_src[p] = src[e];
}

// ============ fused 4-way linear: q,k,v = x@W+b ; skip -> hout ============
__global__ void fused_qkvs(const float* __restrict__ x, int N, int Din,
                           const float* __restrict__ Wq, const float* __restrict__ bq,
                           const float* __restrict__ Wk, const float* __restrict__ bk,
                           const float* __restrict__ Wv, const float* __restrict__ bv,
                           const float* __restrict__ Ws, const float* __restrict__ bs,
                           float* __restrict__ q, float* __restrict__ k,
                           float* __restrict__ v, float* __restrict__ hout)
{
    __shared__ float xs[16][IN_DIM];
    const int row0 = blockIdx.x * 16;
    const int tid  = threadIdx.x;

    for (int idx = tid; idx < 16 * Din; idx += 256) {
        int r = idx / Din, c = idx - r * Din;
        int gr = row0 + r;
        xs[r][c] = (gr < N) ? x[gr * Din + c] : 0.f;
    }
    __syncthreads();

    const int col  = tid & 63;
    const int rgrp = tid >> 6;

    float aq[4] = {0,0,0,0}, ak[4] = {0,0,0,0}, av[4] = {0,0,0,0}, as_[4] = {0,0,0,0};
    for (int kk = 0; kk < Din; ++kk) {
        float wq = Wq[kk * 64 + col];
        float wk = Wk[kk * 64 + col];
        float wv = Wv[kk * 64 + col];
        float ws = Ws[kk * 64 + col];
        #pragma unroll
        for (int e = 0; e < 4; ++e) {
            float xv = xs[rgrp * 4 + e][kk];
            aq[e] = fmaf(xv, wq, aq[e]);
            ak[e] = fmaf(xv, wk, ak[e]);
            av[e] = fmaf(xv, wv, av[e]);
            as_[e] = fmaf(xv, ws, as_[e]);
        }
    }
    #pragma unroll
    for (int e = 0; e < 4; ++e) {
        int row = row0 + rgrp * 4 + e;
        if (row < N) {
            q[row * 64 + col]    = aq[e] + bq[col];
            k[row * 64 + col]    = ak[e] + bk[col];
            v[row * 64 + col]    = av[e] + bv[col];
            hout[row * 64 + col] = as_[e] + bs[col];  // skip path; agg added in node_agg
        }
    }
}

// ============ edge scores -> CSR slot order ============
__global__ void edge_scores(const float* __restrict__ q, const float* __restrict__ k,
                            const int* __restrict__ src, const int* __restrict__ dst,
                            const int* __restrict__ slot,
                            float* __restrict__ scores_csr, int E)
{
    int idx  = blockIdx.x * blockDim.x + threadIdx.x;
    int e    = idx >> 4;
    int lane = idx & 15;
    if (e >= E) return;
    int s = src[e], d = dst[e];
    float4 qv = ((const float4*)(q + (size_t)d * 64))[lane];
    float4 kv = ((const float4*)(k + (size_t)s * 64))[lane];
    float acc = qv.x * kv.x + qv.y * kv.y + qv.z * kv.z + qv.w * kv.w;
    acc += __shfl_xor(acc, 1);
    acc += __shfl_xor(acc, 2);
    acc += __shfl_xor(acc, 4);
    acc += __shfl_xor(acc, 8);
    if (lane == 0) scores_csr[slot[e]] = acc * 0.125f;  // / sqrt(64)
}

// ============ per-node softmax + aggregation + skip + relu (no atomics) ============
__global__ __launch_bounds__(256) void node_agg(
    const float* __restrict__ v, const float* __restrict__ scores_csr,
    const int* __restrict__ csr_src, const int* __restrict__ row_start,
    float* __restrict__ csr_exp, float* __restrict__ hout, int N)
{
    int node = blockIdx.x * 4 + (threadIdx.x >> 6);
    int lane = threadIdx.x & 63;
    if (node >= N) return;
    int start = row_start[node], end = row_start[node + 1];

    // segment max (lane-parallel over edges)
    float m = -__builtin_inff();
    for (int j = start + lane; j < end; j += 64) m = fmaxf(m, scores_csr[j]);
    #pragma unroll
    for (int off = 1; off < 64; off <<= 1) m = fmaxf(m, __shfl_xor(m, off));

    // exp + denom
    float ssum = 0.f;
    for (int j = start + lane; j < end; j += 64) {
        float ex = expf(scores_csr[j] - m);
        csr_exp[j] = ex;
        ssum += ex;
    }
    #pragma unroll
    for (int off = 1; off < 64; off <<= 1) ssum += __shfl_xor(ssum, off);
    float inv = 1.f / (ssum + 1e-16f);

    // aggregate: acc[lane] = sum_j alpha_j * v[src_j][lane]
    float acc = 0.f;
    for (int j = start; j < end; ++j) {
        int s  = csr_src[j];              // uniform across wave -> broadcast
        float a = csr_exp[j] * inv;       // uniform across wave -> broadcast
        acc = fmaf(a, v[(size_t)s * 64 + lane], acc);
    }

    size_t o = (size_t)node * 64 + lane;
    hout[o] = fmaxf(hout[o] + acc, 0.f);  // skip + agg + relu fused
}

// ============ pool + MLP ============
__global__ void zero_f(float* p, int n) {
    int i = blockIdx.x * blockDim.x + threadIdx.x;
    if (i < n) p[i] = 0.f;
}

__global__ void pool_kernel(const float* __restrict__ h, const int* __restrict__ batch,
                            float* __restrict__ pooled, int N)
{
    int col  = threadIdx.x;           // 64 threads
    int base = blockIdx.x * 512;
    int end  = base + 512; if (end > N) end = N;
    int gcur = -1; float acc = 0.f;
    for (int i = base; i < end; ++i) {
        int g = batch[i];
        if (g != gcur) {
            if (gcur >= 0) atomicAdd(&pooled[gcur * 64 + col], acc);
            gcur = g; acc = 0.f;
        }
        acc += h[(size_t)i * 64 + col];
    }
    if (gcur >= 0) atomicAdd(&pooled[gcur * 64 + col], acc);
}

__global__ void mlp1(const float* __restrict__ pooled, const float* __restrict__ W1,
                     const float* __restrict__ b1, float* __restrict__ hidden)
{
    int idx = blockIdx.x * blockDim.x + threadIdx.x;
    if (idx >= N_GRAPHS * 64) return;
    int g = idx >> 6, c = idx & 63;
    float acc = b1[c];
    for (int kk = 0; kk < 64; ++kk)
        acc = fmaf(pooled[g * 64 + kk], W1[kk * 64 + c], acc);
    hidden[idx] = fmaxf(acc, 0.f);
}

__global__ void mlp2(const float* __restrict__ hidden, const float* __restrict__ W2,
                     const float* __restrict__ b2, float* __restrict__ out)
{
    int idx = blockIdx.x * blockDim.x + threadIdx.x;
    if (idx >= N_GRAPHS * 16) return;
    int g = idx >> 4, c = idx & 15;
    float acc = b2[c];
    for (int kk = 0; kk < 64; ++kk)
        acc = fmaf(hidden[g * 64 + kk], W2[kk * 16 + c], acc);
    out[idx] = acc;
}

extern "C" void kernel_launch(void* const* d_in, const int* in_sizes, int n_in,
                              void* d_out, int out_size, void* d_ws, size_t ws_size,
                              hipStream_t stream)
{
    const float* x   = (const float*)d_in[0];
    const float* Wq0 = (const float*)d_in[1];  const float* bq0 = (const float*)d_in[2];
    const float* Wk0 = (const float*)d_in[3];  const float* bk0 = (const float*)d_in[4];
    const float* Wv0 = (const float*)d_in[5];  const float* bv0 = (const float*)d_in[6];
    const float* Ws0 = (const float*)d_in[7];  const float* bs0 = (const float*)d_in[8];
    const float* Wqs = (const float*)d_in[9];  const float* bqs = (const float*)d_in[10];
    const float* Wks = (const float*)d_in[11]; const float* bks = (const float*)d_in[12];
    const float* Wvs = (const float*)d_in[13]; const float* bvs = (const float*)d_in[14];
    const float* Wss = (const float*)d_in[15]; const float* bss = (const float*)d_in[16];
    const float* W1  = (const float*)d_in[17]; const float* b1  = (const float*)d_in[18];
    const float* W2  = (const float*)d_in[19]; const float* b2  = (const float*)d_in[20];
    const int*   ei  = (const int*)d_in[21];
    const int*   batch = (const int*)d_in[22];
    float* out = (float*)d_out;

    const int* src = ei;
    const int* dst = ei + N_EDGES;

    const size_t NH = (size_t)N_NODES * 64;
    float* q        = (float*)d_ws;
    float* k        = q + NH;
    float* v        = k + NH;
    float* hA       = v + NH;
    float* hB       = hA + NH;
    float* scores   = hB + NH;          // CSR slot order
    float* csr_exp  = scores + N_EDGES;
    int*   csr_src  = (int*)(csr_exp + N_EDGES);
    int*   slot     = csr_src + N_EDGES;
    int*   row_start= slot + N_EDGES;           // N_NODES+1
    int*   cursor   = row_start + N_NODES + 1;  // N_NODES
    int*   counts   = cursor + N_NODES;         // N_NODES (also 'pre' after scan1)
    int*   blockSums= counts + N_NODES;         // 512
    float* pooled   = (float*)(blockSums + 512);
    float* hidden   = pooled + N_GRAPHS * 64;

    struct LW { const float *Wq,*bq,*Wk,*bk,*Wv,*bv,*Ws,*bs; };
    LW lw[3] = {
        { Wq0, bq0, Wk0, bk0, Wv0, bv0, Ws0, bs0 },
        { Wqs, bqs, Wks, bks, Wvs, bvs, Wss, bss },
        { Wqs + 4096, bqs + 64, Wks + 4096, bks + 64, Wvs + 4096, bvs + 64, Wss + 4096, bss + 64 }
    };
    const float* lin_in[3]  = { x, hA, hB };
    int          lin_dim[3] = { IN_DIM, HID, HID };
    float*       lin_out[3] = { hA, hB, hA };

    const int nodeBlocks   = (N_NODES + 255) / 256;
    const int edgeBlocks   = (N_EDGES + 255) / 256;
    const int edgeBlocks16 = (N_EDGES * 16 + 255) / 256;
    const int scanBlocks   = (N_NODES + 255) / 256;   // 391

    // ---- CSR build (once; edge_index constant across layers) ----
    zero_i<<<nodeBlocks, 256, 0, stream>>>(counts, N_NODES);
    count_deg<<<edgeBlocks, 256, 0, stream>>>(dst, counts, N_EDGES);
    scan1<<<scanBlocks, 256, 0, stream>>>(counts, counts, blockSums, N_NODES); // in-place pre
    scan2<<<1, 512, 0, stream>>>(blockSums, scanBlocks);
    scan3<<<(N_NODES + 256) / 256, 256, 0, stream>>>(counts, blockSums, row_start, cursor,
                                                     N_NODES, N_EDGES);
    csr_fill<<<edgeBlocks, 256, 0, stream>>>(src, dst, cursor, slot, csr_src, N_EDGES);

    // ---- 3 TransformerConv layers ----
    const int linBlocks = (N_NODES + 15) / 16;
    for (int L = 0; L < 3; ++L) {
        fused_qkvs<<<linBlocks, 256, 0, stream>>>(lin_in[L], N_NODES, lin_dim[L],
            lw[L].Wq, lw[L].bq, lw[L].Wk, lw[L].bk, lw[L].Wv, lw[L].bv, lw[L].Ws, lw[L].bs,
            q, k, v, lin_out[L]);
        edge_scores<<<edgeBlocks16, 256, 0, stream>>>(q, k, src, dst, slot, scores, N_EDGES);
        node_agg<<<(N_NODES + 3) / 4, 256, 0, stream>>>(v, scores, csr_src, row_start,
                                                        csr_exp, lin_out[L], N_NODES);
    }

    // ---- pool + MLP ----
    zero_f<<<(N_GRAPHS * 64 + 255) / 256, 256, 0, stream>>>(pooled, N_GRAPHS * 64);
    pool_kernel<<<(N_NODES + 511) / 512, 64, 0, stream>>>(hA, batch, pooled, N_NODES);
    mlp1<<<(N_GRAPHS * 64 + 255) / 256, 256, 0, stream>>>(pooled, W1, b1, hidden);
    mlp2<<<(N_GRAPHS * 16 + 255) / 256, 256, 0, stream>>>(hidden, W2, b2, out);
}

// Round 8
// 1363.874 us; speedup vs baseline: 3.7688x; 1.0988x over previous
//
#include <hip/hip_runtime.h>
#include <hip/hip_bf16.h>

#define N_NODES 100000
#define N_EDGES 1600000
#define IN_DIM  128
#define HID     64
#define N_GRAPHS 500

// ============ CSR build ============
__global__ void zero_i(int* p, int n) {
    int i = blockIdx.x * blockDim.x + threadIdx.x;
    if (i < n) p[i] = 0;
}

__global__ void count_deg(const int* __restrict__ dst, int* __restrict__ counts, int E) {
    int e = blockIdx.x * blockDim.x + threadIdx.x;
    if (e < E) atomicAdd(&counts[dst[e]], 1);
}

// per-block exclusive scan of 256 elements + block total
__global__ void scan1(const int* __restrict__ counts, int* __restrict__ pre,
                      int* __restrict__ blockSums, int n) {
    __shared__ int tmp[256];
    int tid = threadIdx.x;
    int i = blockIdx.x * 256 + tid;
    int v = (i < n) ? counts[i] : 0;
    tmp[tid] = v; __syncthreads();
    int acc = v;
    for (int off = 1; off < 256; off <<= 1) {
        int add = (tid >= off) ? tmp[tid - off] : 0;
        __syncthreads();
        acc += add; tmp[tid] = acc;
        __syncthreads();
    }
    if (i < n) pre[i] = acc - v;
    if (tid == 255) blockSums[blockIdx.x] = acc;
}

// exclusive scan of <=512 block sums, in place (single block of 512)
__global__ void scan2(int* blockSums, int nb) {
    __shared__ int tmp[512];
    int tid = threadIdx.x;
    int v = (tid < nb) ? blockSums[tid] : 0;
    tmp[tid] = v; __syncthreads();
    int acc = v;
    for (int off = 1; off < 512; off <<= 1) {
        int add = (tid >= off) ? tmp[tid - off] : 0;
        __syncthreads();
        acc += add; tmp[tid] = acc;
        __syncthreads();
    }
    if (tid < nb) blockSums[tid] = acc - v;
}

__global__ void scan3(const int* __restrict__ pre, const int* __restrict__ blockSums,
                      int* __restrict__ row_start, int* __restrict__ cursor, int n, int E) {
    int i = blockIdx.x * blockDim.x + threadIdx.x;
    if (i < n) {
        int r = pre[i] + blockSums[i >> 8];
        row_start[i] = r;
        cursor[i] = r;
    } else if (i == n) {
        row_start[n] = E;
    }
}

// csr_src[p] = src of edge at CSR position p; csr_dst[p] = its dst
__global__ void csr_fill(const int* __restrict__ src, const int* __restrict__ dst,
                         int* __restrict__ cursor, int* __restrict__ csr_src,
                         int* __restrict__ csr_dst, int E) {
    int e = blockIdx.x * blockDim.x + threadIdx.x;
    if (e >= E) return;
    int d = dst[e];
    int p = atomicAdd(&cursor[d], 1);
    csr_src[p] = src[e];
    csr_dst[p] = d;
}

// ============ fused 4-way linear: q,k,v = x@W+b ; skip -> hout ============
// 256 threads, 32 rows/block, 8 rows per thread (col = tid&63).
template<int DIN>
__global__ __launch_bounds__(256) void fused_qkvs(
    const float* __restrict__ x, int N,
    const float* __restrict__ Wq, const float* __restrict__ bq,
    const float* __restrict__ Wk, const float* __restrict__ bk,
    const float* __restrict__ Wv, const float* __restrict__ bv,
    const float* __restrict__ Ws, const float* __restrict__ bs,
    float* __restrict__ q, float* __restrict__ k,
    float* __restrict__ v, float* __restrict__ hout)
{
    __shared__ float xs[32][DIN];
    const int row0 = blockIdx.x * 32;
    const int tid  = threadIdx.x;

    constexpr int D4 = DIN / 4;
    for (int idx = tid; idx < 32 * D4; idx += 256) {
        int r = idx / D4, c4 = idx - r * D4;
        int gr = row0 + r;
        float4 val = (gr < N) ? ((const float4*)(x + (size_t)gr * DIN))[c4]
                              : make_float4(0.f, 0.f, 0.f, 0.f);
        ((float4*)xs[r])[c4] = val;
    }
    __syncthreads();

    const int col = tid & 63;
    const int rg  = tid >> 6;   // 0..3 -> rows rg*8 .. rg*8+7

    float aq[8], ak[8], av[8], as_[8];
    #pragma unroll
    for (int e = 0; e < 8; ++e) { aq[e] = 0.f; ak[e] = 0.f; av[e] = 0.f; as_[e] = 0.f; }

    #pragma unroll 8
    for (int kk = 0; kk < DIN; ++kk) {
        float wq = Wq[kk * 64 + col];
        float wk = Wk[kk * 64 + col];
        float wv = Wv[kk * 64 + col];
        float ws = Ws[kk * 64 + col];
        #pragma unroll
        for (int e = 0; e < 8; ++e) {
            float xv = xs[rg * 8 + e][kk];   // same addr across wave -> broadcast
            aq[e]  = fmaf(xv, wq, aq[e]);
            ak[e]  = fmaf(xv, wk, ak[e]);
            av[e]  = fmaf(xv, wv, av[e]);
            as_[e] = fmaf(xv, ws, as_[e]);
        }
    }

    const float vbq = bq[col], vbk = bk[col], vbv = bv[col], vbs = bs[col];
    #pragma unroll
    for (int e = 0; e < 8; ++e) {
        int row = row0 + rg * 8 + e;
        if (row < N) {
            q[(size_t)row * 64 + col]    = aq[e] + vbq;
            k[(size_t)row * 64 + col]    = ak[e] + vbk;
            v[(size_t)row * 64 + col]    = av[e] + vbv;
            hout[(size_t)row * 64 + col] = as_[e] + vbs;  // skip; agg added in node_agg
        }
    }
}

// ============ edge scores in CSR order (coalesced write, run-contiguous q reads) ===
__global__ void edge_scores(const float* __restrict__ q, const float* __restrict__ k,
                            const int* __restrict__ csr_src, const int* __restrict__ csr_dst,
                            float* __restrict__ scores_csr, int E)
{
    int idx  = blockIdx.x * blockDim.x + threadIdx.x;
    int p    = idx >> 4;
    int lane = idx & 15;
    if (p >= E) return;
    int s = csr_src[p], d = csr_dst[p];
    float4 qv = ((const float4*)(q + (size_t)d * 64))[lane];
    float4 kv = ((const float4*)(k + (size_t)s * 64))[lane];
    float acc = qv.x * kv.x + qv.y * kv.y + qv.z * kv.z + qv.w * kv.w;
    acc += __shfl_xor(acc, 1);
    acc += __shfl_xor(acc, 2);
    acc += __shfl_xor(acc, 4);
    acc += __shfl_xor(acc, 8);
    if (lane == 0) scores_csr[p] = acc * 0.125f;  // / sqrt(64)
}

// ============ per-node softmax + aggregation + skip + relu (no atomics) ============
__global__ __launch_bounds__(256) void node_agg(
    const float* __restrict__ v, const float* __restrict__ scores_csr,
    const int* __restrict__ csr_src, const int* __restrict__ row_start,
    float* __restrict__ csr_exp, float* __restrict__ hout, int N)
{
    int node = blockIdx.x * 4 + (threadIdx.x >> 6);
    int lane = threadIdx.x & 63;
    if (node >= N) return;
    int start = row_start[node], end = row_start[node + 1];

    float m = -__builtin_inff();
    for (int j = start + lane; j < end; j += 64) m = fmaxf(m, scores_csr[j]);
    #pragma unroll
    for (int off = 1; off < 64; off <<= 1) m = fmaxf(m, __shfl_xor(m, off));

    float ssum = 0.f;
    for (int j = start + lane; j < end; j += 64) {
        float ex = expf(scores_csr[j] - m);
        csr_exp[j] = ex;
        ssum += ex;
    }
    #pragma unroll
    for (int off = 1; off < 64; off <<= 1) ssum += __shfl_xor(ssum, off);
    float inv = 1.f / (ssum + 1e-16f);

    float acc = 0.f;
    for (int j = start; j < end; ++j) {
        int s   = csr_src[j];          // uniform across wave -> broadcast
        float a = csr_exp[j] * inv;    // uniform across wave -> broadcast
        acc = fmaf(a, v[(size_t)s * 64 + lane], acc);
    }

    size_t o = (size_t)node * 64 + lane;
    hout[o] = fmaxf(hout[o] + acc, 0.f);  // skip + agg + relu fused
}

// ============ pool + MLP ============
__global__ void zero_f(float* p, int n) {
    int i = blockIdx.x * blockDim.x + threadIdx.x;
    if (i < n) p[i] = 0.f;
}

// 256 threads: 4 row-lanes x 64 cols; block covers 128 rows.
__global__ void pool_kernel(const float* __restrict__ h, const int* __restrict__ batch,
                            float* __restrict__ pooled, int N)
{
    int col = threadIdx.x & 63;
    int rg  = threadIdx.x >> 6;
    int base = blockIdx.x * 128;
    int end  = base + 128; if (end > N) end = N;
    int gcur = -1; float acc = 0.f;
    for (int i = base + rg; i < end; i += 4) {
        int g = batch[i];
        if (g != gcur) {
            if (gcur >= 0) atomicAdd(&pooled[gcur * 64 + col], acc);
            gcur = g; acc = 0.f;
        }
        acc += h[(size_t)i * 64 + col];
    }
    if (gcur >= 0) atomicAdd(&pooled[gcur * 64 + col], acc);
}

__global__ void mlp1(const float* __restrict__ pooled, const float* __restrict__ W1,
                     const float* __restrict__ b1, float* __restrict__ hidden)
{
    int idx = blockIdx.x * blockDim.x + threadIdx.x;
    if (idx >= N_GRAPHS * 64) return;
    int g = idx >> 6, c = idx & 63;
    float acc = b1[c];
    for (int kk = 0; kk < 64; ++kk)
        acc = fmaf(pooled[g * 64 + kk], W1[kk * 64 + c], acc);
    hidden[idx] = fmaxf(acc, 0.f);
}

__global__ void mlp2(const float* __restrict__ hidden, const float* __restrict__ W2,
                     const float* __restrict__ b2, float* __restrict__ out)
{
    int idx = blockIdx.x * blockDim.x + threadIdx.x;
    if (idx >= N_GRAPHS * 16) return;
    int g = idx >> 4, c = idx & 15;
    float acc = b2[c];
    for (int kk = 0; kk < 64; ++kk)
        acc = fmaf(hidden[g * 64 + kk], W2[kk * 16 + c], acc);
    out[idx] = acc;
}

extern "C" void kernel_launch(void* const* d_in, const int* in_sizes, int n_in,
                              void* d_out, int out_size, void* d_ws, size_t ws_size,
                              hipStream_t stream)
{
    const float* x   = (const float*)d_in[0];
    const float* Wq0 = (const float*)d_in[1];  const float* bq0 = (const float*)d_in[2];
    const float* Wk0 = (const float*)d_in[3];  const float* bk0 = (const float*)d_in[4];
    const float* Wv0 = (const float*)d_in[5];  const float* bv0 = (const float*)d_in[6];
    const float* Ws0 = (const float*)d_in[7];  const float* bs0 = (const float*)d_in[8];
    const float* Wqs = (const float*)d_in[9];  const float* bqs = (const float*)d_in[10];
    const float* Wks = (const float*)d_in[11]; const float* bks = (const float*)d_in[12];
    const float* Wvs = (const float*)d_in[13]; const float* bvs = (const float*)d_in[14];
    const float* Wss = (const float*)d_in[15]; const float* bss = (const float*)d_in[16];
    const float* W1  = (const float*)d_in[17]; const float* b1  = (const float*)d_in[18];
    const float* W2  = (const float*)d_in[19]; const float* b2  = (const float*)d_in[20];
    const int*   ei  = (const int*)d_in[21];
    const int*   batch = (const int*)d_in[22];
    float* out = (float*)d_out;

    const int* src = ei;
    const int* dst = ei + N_EDGES;

    const size_t NH = (size_t)N_NODES * 64;
    float* q        = (float*)d_ws;
    float* k        = q + NH;
    float* v        = k + NH;
    float* hA       = v + NH;
    float* hB       = hA + NH;
    float* scores   = hB + NH;          // CSR order
    float* csr_exp  = scores + N_EDGES;
    int*   csr_src  = (int*)(csr_exp + N_EDGES);
    int*   csr_dst  = csr_src + N_EDGES;
    int*   row_start= csr_dst + N_EDGES;        // N_NODES+1
    int*   cursor   = row_start + N_NODES + 1;  // N_NODES
    int*   counts   = cursor + N_NODES;         // N_NODES
    int*   blockSums= counts + N_NODES;         // 512
    float* pooled   = (float*)(blockSums + 512);
    float* hidden   = pooled + N_GRAPHS * 64;

    struct LW { const float *Wq,*bq,*Wk,*bk,*Wv,*bv,*Ws,*bs; };
    LW lw[3] = {
        { Wq0, bq0, Wk0, bk0, Wv0, bv0, Ws0, bs0 },
        { Wqs, bqs, Wks, bks, Wvs, bvs, Wss, bss },
        { Wqs + 4096, bqs + 64, Wks + 4096, bks + 64, Wvs + 4096, bvs + 64, Wss + 4096, bss + 64 }
    };

    const int nodeBlocks   = (N_NODES + 255) / 256;
    const int edgeBlocks   = (N_EDGES + 255) / 256;
    const int edgeBlocks16 = (N_EDGES * 16 + 255) / 256;
    const int scanBlocks   = (N_NODES + 255) / 256;   // 391

    // ---- CSR build (once; edge_index constant across layers) ----
    zero_i<<<nodeBlocks, 256, 0, stream>>>(counts, N_NODES);
    count_deg<<<edgeBlocks, 256, 0, stream>>>(dst, counts, N_EDGES);
    scan1<<<scanBlocks, 256, 0, stream>>>(counts, counts, blockSums, N_NODES);
    scan2<<<1, 512, 0, stream>>>(blockSums, scanBlocks);
    scan3<<<(N_NODES + 256) / 256, 256, 0, stream>>>(counts, blockSums, row_start, cursor,
                                                     N_NODES, N_EDGES);
    csr_fill<<<edgeBlocks, 256, 0, stream>>>(src, dst, cursor, csr_src, csr_dst, N_EDGES);

    // ---- 3 TransformerConv layers ----
    const int linBlocks = (N_NODES + 31) / 32;
    for (int L = 0; L < 3; ++L) {
        if (L == 0) {
            fused_qkvs<IN_DIM><<<linBlocks, 256, 0, stream>>>(x, N_NODES,
                lw[0].Wq, lw[0].bq, lw[0].Wk, lw[0].bk, lw[0].Wv, lw[0].bv, lw[0].Ws, lw[0].bs,
                q, k, v, hA);
        } else {
            const float* hin = (L == 1) ? hA : hB;
            float* hou       = (L == 1) ? hB : hA;
            fused_qkvs<HID><<<linBlocks, 256, 0, stream>>>(hin, N_NODES,
                lw[L].Wq, lw[L].bq, lw[L].Wk, lw[L].bk, lw[L].Wv, lw[L].bv, lw[L].Ws, lw[L].bs,
                q, k, v, hou);
        }
        float* hou = (L == 0) ? hA : ((L == 1) ? hB : hA);
        edge_scores<<<edgeBlocks16, 256, 0, stream>>>(q, k, csr_src, csr_dst, scores, N_EDGES);
        node_agg<<<(N_NODES + 3) / 4, 256, 0, stream>>>(v, scores, csr_src, row_start,
                                                        csr_exp, hou, N_NODES);
    }

    // ---- pool + MLP ----
    zero_f<<<(N_GRAPHS * 64 + 255) / 256, 256, 0, stream>>>(pooled, N_GRAPHS * 64);
    pool_kernel<<<(N_NODES + 127) / 128, 256, 0, stream>>>(hA, batch, pooled, N_NODES);
    mlp1<<<(N_GRAPHS * 64 + 255) / 256, 256, 0, stream>>>(pooled, W1, b1, hidden);
    mlp2<<<(N_GRAPHS * 16 + 255) / 256, 256, 0, stream>>>(hidden, W2, b2, out);
}

// Round 10
// 1117.982 us; speedup vs baseline: 4.5977x; 1.2199x over previous
//
#include <hip/hip_runtime.h>
#include <hip/hip_bf16.h>

#define N_NODES 100000
#define N_EDGES 1600000
#define IN_DIM  128
#define HID     64
#define N_GRAPHS 500

// ============ CSR build ============
__global__ void zero_i(int* p, int n) {
    int i = blockIdx.x * blockDim.x + threadIdx.x;
    if (i < n) p[i] = 0;
}

__global__ void count_deg(const int* __restrict__ dst, int* __restrict__ counts, int E) {
    int e = blockIdx.x * blockDim.x + threadIdx.x;
    if (e < E) atomicAdd(&counts[dst[e]], 1);
}

// per-block exclusive scan of 256 elements + block total
__global__ void scan1(const int* __restrict__ counts, int* __restrict__ pre,
                      int* __restrict__ blockSums, int n) {
    __shared__ int tmp[256];
    int tid = threadIdx.x;
    int i = blockIdx.x * 256 + tid;
    int v = (i < n) ? counts[i] : 0;
    tmp[tid] = v; __syncthreads();
    int acc = v;
    for (int off = 1; off < 256; off <<= 1) {
        int add = (tid >= off) ? tmp[tid - off] : 0;
        __syncthreads();
        acc += add; tmp[tid] = acc;
        __syncthreads();
    }
    if (i < n) pre[i] = acc - v;
    if (tid == 255) blockSums[blockIdx.x] = acc;
}

// exclusive scan of <=512 block sums, in place (single block of 512)
__global__ void scan2(int* blockSums, int nb) {
    __shared__ int tmp[512];
    int tid = threadIdx.x;
    int v = (tid < nb) ? blockSums[tid] : 0;
    tmp[tid] = v; __syncthreads();
    int acc = v;
    for (int off = 1; off < 512; off <<= 1) {
        int add = (tid >= off) ? tmp[tid - off] : 0;
        __syncthreads();
        acc += add; tmp[tid] = acc;
        __syncthreads();
    }
    if (tid < nb) blockSums[tid] = acc - v;
}

__global__ void scan3(const int* __restrict__ pre, const int* __restrict__ blockSums,
                      int* __restrict__ row_start, int* __restrict__ cursor, int n, int E) {
    int i = blockIdx.x * blockDim.x + threadIdx.x;
    if (i < n) {
        int r = pre[i] + blockSums[i >> 8];
        row_start[i] = r;
        cursor[i] = r;
    } else if (i == n) {
        row_start[n] = E;
    }
}

// csr_src[p] = src of edge at CSR position p; csr_dst[p] = its dst
__global__ void csr_fill(const int* __restrict__ src, const int* __restrict__ dst,
                         int* __restrict__ cursor, int* __restrict__ csr_src,
                         int* __restrict__ csr_dst, int E) {
    int e = blockIdx.x * blockDim.x + threadIdx.x;
    if (e >= E) return;
    int d = dst[e];
    int p = atomicAdd(&cursor[d], 1);
    csr_src[p] = src[e];
    csr_dst[p] = d;
}

// ============ qkvs via tiled GEMM ============
// C[64rows x 64cols] tile of ONE matrix per block. blockIdx.x = matrix (0..3),
// blockIdx.y = row tile. 256 threads, 4x4 micro-tile, BK=32 double-operand LDS.
template<int DIN>
__global__ __launch_bounds__(256) void qkvs_gemm(
    const float* __restrict__ x, int N,
    const float* __restrict__ Wq, const float* __restrict__ bq,
    const float* __restrict__ Wk, const float* __restrict__ bk,
    const float* __restrict__ Wv, const float* __restrict__ bv,
    const float* __restrict__ Ws, const float* __restrict__ bs,
    float* __restrict__ q, float* __restrict__ k,
    float* __restrict__ v, float* __restrict__ hout)
{
    constexpr int BM = 64, BK = 32;
    __shared__ float As[BK][BM + 1];   // x tile, transposed; +1 pad
    __shared__ float Bs[BK][64];       // W tile

    const int by = blockIdx.x;         // matrix id: consecutive blocks share x-tile (L2)
    const float* W    = (by == 0) ? Wq : (by == 1) ? Wk : (by == 2) ? Wv : Ws;
    const float* bias = (by == 0) ? bq : (by == 1) ? bk : (by == 2) ? bv : bs;
    float*       outp = (by == 0) ? q  : (by == 1) ? k  : (by == 2) ? v  : hout;

    const int row0 = blockIdx.y * BM;
    const int tid  = threadIdx.x;
    const int tx   = (tid & 15) * 4;   // col 0..60
    const int ty   = (tid >> 4) * 4;   // row 0..60

    float acc[4][4] = {};

    for (int k0 = 0; k0 < DIN; k0 += BK) {
        // stage x tile transposed: x[row0+r][k0+c4*4 ..] -> As[kk][r]
        #pragma unroll
        for (int h = 0; h < 2; ++h) {
            int idx = tid + h * 256;
            int r   = idx >> 3, c4 = idx & 7;
            int gr  = row0 + r;
            float4 val = (gr < N) ? *(const float4*)(x + (size_t)gr * DIN + k0 + c4 * 4)
                                  : make_float4(0.f, 0.f, 0.f, 0.f);
            int kk = c4 * 4;
            As[kk + 0][r] = val.x;
            As[kk + 1][r] = val.y;
            As[kk + 2][r] = val.z;
            As[kk + 3][r] = val.w;
        }
        // stage W tile: W[k0+kr][0:64] row-major, coalesced
        #pragma unroll
        for (int h = 0; h < 2; ++h) {
            int kr = (tid >> 4) + h * 16;
            int n4 = (tid & 15) * 4;
            *(float4*)(&Bs[kr][n4]) = *(const float4*)(W + (size_t)(k0 + kr) * 64 + n4);
        }
        __syncthreads();

        #pragma unroll
        for (int kk = 0; kk < BK; ++kk) {
            float4 a = *(const float4*)(&As[kk][ty]);
            float4 b = *(const float4*)(&Bs[kk][tx]);
            acc[0][0] = fmaf(a.x, b.x, acc[0][0]);
            acc[0][1] = fmaf(a.x, b.y, acc[0][1]);
            acc[0][2] = fmaf(a.x, b.z, acc[0][2]);
            acc[0][3] = fmaf(a.x, b.w, acc[0][3]);
            acc[1][0] = fmaf(a.y, b.x, acc[1][0]);
            acc[1][1] = fmaf(a.y, b.y, acc[1][1]);
            acc[1][2] = fmaf(a.y, b.z, acc[1][2]);
            acc[1][3] = fmaf(a.y, b.w, acc[1][3]);
            acc[2][0] = fmaf(a.z, b.x, acc[2][0]);
            acc[2][1] = fmaf(a.z, b.y, acc[2][1]);
            acc[2][2] = fmaf(a.z, b.z, acc[2][2]);
            acc[2][3] = fmaf(a.z, b.w, acc[2][3]);
            acc[3][0] = fmaf(a.w, b.x, acc[3][0]);
            acc[3][1] = fmaf(a.w, b.y, acc[3][1]);
            acc[3][2] = fmaf(a.w, b.z, acc[3][2]);
            acc[3][3] = fmaf(a.w, b.w, acc[3][3]);
        }
        __syncthreads();
    }

    float4 bv4 = *(const float4*)(bias + tx);
    #pragma unroll
    for (int i = 0; i < 4; ++i) {
        int row = row0 + ty + i;
        if (row < N) {
            float4 o = make_float4(acc[i][0] + bv4.x, acc[i][1] + bv4.y,
                                   acc[i][2] + bv4.z, acc[i][3] + bv4.w);
            *(float4*)(outp + (size_t)row * 64 + tx) = o;
        }
    }
}

// ============ edge scores in CSR order ============
__global__ void edge_scores(const float* __restrict__ q, const float* __restrict__ k,
                            const int* __restrict__ csr_src, const int* __restrict__ csr_dst,
                            float* __restrict__ scores_csr, int E)
{
    int idx  = blockIdx.x * blockDim.x + threadIdx.x;
    int p    = idx >> 4;
    int lane = idx & 15;
    if (p >= E) return;
    int s = csr_src[p], d = csr_dst[p];
    float4 qv = ((const float4*)(q + (size_t)d * 64))[lane];
    float4 kv = ((const float4*)(k + (size_t)s * 64))[lane];
    float acc = qv.x * kv.x + qv.y * kv.y + qv.z * kv.z + qv.w * kv.w;
    acc += __shfl_xor(acc, 1);
    acc += __shfl_xor(acc, 2);
    acc += __shfl_xor(acc, 4);
    acc += __shfl_xor(acc, 8);
    if (lane == 0) scores_csr[p] = acc * 0.125f;  // / sqrt(64)
}

// ============ per-node softmax + aggregation + skip + relu (no atomics) ============
__global__ __launch_bounds__(256) void node_agg(
    const float* __restrict__ v, const float* __restrict__ scores_csr,
    const int* __restrict__ csr_src, const int* __restrict__ row_start,
    float* __restrict__ csr_exp, float* __restrict__ hout, int N)
{
    int node = blockIdx.x * 4 + (threadIdx.x >> 6);
    int lane = threadIdx.x & 63;
    if (node >= N) return;
    int start = row_start[node], end = row_start[node + 1];

    float m = -__builtin_inff();
    for (int j = start + lane; j < end; j += 64) m = fmaxf(m, scores_csr[j]);
    #pragma unroll
    for (int off = 1; off < 64; off <<= 1) m = fmaxf(m, __shfl_xor(m, off));

    float ssum = 0.f;
    for (int j = start + lane; j < end; j += 64) {
        float ex = expf(scores_csr[j] - m);
        csr_exp[j] = ex;
        ssum += ex;
    }
    #pragma unroll
    for (int off = 1; off < 64; off <<= 1) ssum += __shfl_xor(ssum, off);
    float inv = 1.f / (ssum + 1e-16f);

    float acc = 0.f;
    for (int j = start; j < end; ++j) {
        int s   = csr_src[j];
        float a = csr_exp[j] * inv;
        acc = fmaf(a, v[(size_t)s * 64 + lane], acc);
    }

    size_t o = (size_t)node * 64 + lane;
    hout[o] = fmaxf(hout[o] + acc, 0.f);
}

// ============ pool + MLP ============
__global__ void zero_f(float* p, int n) {
    int i = blockIdx.x * blockDim.x + threadIdx.x;
    if (i < n) p[i] = 0.f;
}

__global__ void pool_kernel(const float* __restrict__ h, const int* __restrict__ batch,
                            float* __restrict__ pooled, int N)
{
    int col = threadIdx.x & 63;
    int rg  = threadIdx.x >> 6;
    int base = blockIdx.x * 128;
    int end  = base + 128; if (end > N) end = N;
    int gcur = -1; float acc = 0.f;
    for (int i = base + rg; i < end; i += 4) {
        int g = batch[i];
        if (g != gcur) {
            if (gcur >= 0) atomicAdd(&pooled[gcur * 64 + col], acc);
            gcur = g; acc = 0.f;
        }
        acc += h[(size_t)i * 64 + col];
    }
    if (gcur >= 0) atomicAdd(&pooled[gcur * 64 + col], acc);
}

__global__ void mlp1(const float* __restrict__ pooled, const float* __restrict__ W1,
                     const float* __restrict__ b1, float* __restrict__ hidden)
{
    int idx = blockIdx.x * blockDim.x + threadIdx.x;
    if (idx >= N_GRAPHS * 64) return;
    int g = idx >> 6, c = idx & 63;
    float acc = b1[c];
    for (int kk = 0; kk < 64; ++kk)
        acc = fmaf(pooled[g * 64 + kk], W1[kk * 64 + c], acc);
    hidden[idx] = fmaxf(acc, 0.f);
}

__global__ void mlp2(const float* __restrict__ hidden, const float* __restrict__ W2,
                     const float* __restrict__ b2, float* __restrict__ out)
{
    int idx = blockIdx.x * blockDim.x + threadIdx.x;
    if (idx >= N_GRAPHS * 16) return;
    int g = idx >> 4, c = idx & 15;
    float acc = b2[c];
    for (int kk = 0; kk < 64; ++kk)
        acc = fmaf(hidden[g * 64 + kk], W2[kk * 16 + c], acc);
    out[idx] = acc;
}

extern "C" void kernel_launch(void* const* d_in, const int* in_sizes, int n_in,
                              void* d_out, int out_size, void* d_ws, size_t ws_size,
                              hipStream_t stream)
{
    const float* x   = (const float*)d_in[0];
    const float* Wq0 = (const float*)d_in[1];  const float* bq0 = (const float*)d_in[2];
    const float* Wk0 = (const float*)d_in[3];  const float* bk0 = (const float*)d_in[4];
    const float* Wv0 = (const float*)d_in[5];  const float* bv0 = (const float*)d_in[6];
    const float* Ws0 = (const float*)d_in[7];  const float* bs0 = (const float*)d_in[8];
    const float* Wqs = (const float*)d_in[9];  const float* bqs = (const float*)d_in[10];
    const float* Wks = (const float*)d_in[11]; const float* bks = (const float*)d_in[12];
    const float* Wvs = (const float*)d_in[13]; const float* bvs = (const float*)d_in[14];
    const float* Wss = (const float*)d_in[15]; const float* bss = (const float*)d_in[16];
    const float* W1  = (const float*)d_in[17]; const float* b1  = (const float*)d_in[18];
    const float* W2  = (const float*)d_in[19]; const float* b2  = (const float*)d_in[20];
    const int*   ei  = (const int*)d_in[21];
    const int*   batch = (const int*)d_in[22];
    float* out = (float*)d_out;

    const int* src = ei;
    const int* dst = ei + N_EDGES;

    const size_t NH = (size_t)N_NODES * 64;
    float* q        = (float*)d_ws;
    float* k        = q + NH;
    float* v        = k + NH;
    float* hA       = v + NH;
    float* hB       = hA + NH;
    float* scores   = hB + NH;          // CSR order
    float* csr_exp  = scores + N_EDGES;
    int*   csr_src  = (int*)(csr_exp + N_EDGES);
    int*   csr_dst  = csr_src + N_EDGES;
    int*   row_start= csr_dst + N_EDGES;        // N_NODES+1
    int*   cursor   = row_start + N_NODES + 1;  // N_NODES
    int*   counts   = cursor + N_NODES;         // N_NODES
    int*   blockSums= counts + N_NODES;         // 512
    float* pooled   = (float*)(blockSums + 512);
    float* hidden   = pooled + N_GRAPHS * 64;

    struct LW { const float *Wq,*bq,*Wk,*bk,*Wv,*bv,*Ws,*bs; };
    LW lw[3] = {
        { Wq0, bq0, Wk0, bk0, Wv0, bv0, Ws0, bs0 },
        { Wqs, bqs, Wks, bks, Wvs, bvs, Wss, bss },
        { Wqs + 4096, bqs + 64, Wks + 4096, bks + 64, Wvs + 4096, bvs + 64, Wss + 4096, bss + 64 }
    };

    const int nodeBlocks   = (N_NODES + 255) / 256;
    const int edgeBlocks   = (N_EDGES + 255) / 256;
    const int edgeBlocks16 = (N_EDGES * 16 + 255) / 256;
    const int scanBlocks   = (N_NODES + 255) / 256;   // 391

    // ---- CSR build (once; edge_index constant across layers) ----
    zero_i<<<nodeBlocks, 256, 0, stream>>>(counts, N_NODES);
    count_deg<<<edgeBlocks, 256, 0, stream>>>(dst, counts, N_EDGES);
    scan1<<<scanBlocks, 256, 0, stream>>>(counts, counts, blockSums, N_NODES);
    scan2<<<1, 512, 0, stream>>>(blockSums, scanBlocks);
    scan3<<<(N_NODES + 256) / 256, 256, 0, stream>>>(counts, blockSums, row_start, cursor,
                                                     N_NODES, N_EDGES);
    csr_fill<<<edgeBlocks, 256, 0, stream>>>(src, dst, cursor, csr_src, csr_dst, N_EDGES);

    // ---- 3 TransformerConv layers ----
    const dim3 gemmGrid(4, (N_NODES + 63) / 64);
    for (int L = 0; L < 3; ++L) {
        if (L == 0) {
            qkvs_gemm<IN_DIM><<<gemmGrid, 256, 0, stream>>>(x, N_NODES,
                lw[0].Wq, lw[0].bq, lw[0].Wk, lw[0].bk, lw[0].Wv, lw[0].bv, lw[0].Ws, lw[0].bs,
                q, k, v, hA);
        } else {
            const float* hin = (L == 1) ? hA : hB;
            float* hou       = (L == 1) ? hB : hA;
            qkvs_gemm<HID><<<gemmGrid, 256, 0, stream>>>(hin, N_NODES,
                lw[L].Wq, lw[L].bq, lw[L].Wk, lw[L].bk, lw[L].Wv, lw[L].bv, lw[L].Ws, lw[L].bs,
                q, k, v, hou);
        }
        float* hou = (L == 0) ? hA : ((L == 1) ? hB : hA);
        edge_scores<<<edgeBlocks16, 256, 0, stream>>>(q, k, csr_src, csr_dst, scores, N_EDGES);
        node_agg<<<(N_NODES + 3) / 4, 256, 0, stream>>>(v, scores, csr_src, row_start,
                                                        csr_exp, hou, N_NODES);
    }

    // ---- pool + MLP ----
    zero_f<<<(N_GRAPHS * 64 + 255) / 256, 256, 0, stream>>>(pooled, N_GRAPHS * 64);
    pool_kernel<<<(N_NODES + 127) / 128, 256, 0, stream>>>(hA, batch, pooled, N_NODES);
    mlp1<<<(N_GRAPHS * 64 + 255) / 256, 256, 0, stream>>>(pooled, W1, b1, hidden);
    mlp2<<<(N_GRAPHS * 16 + 255) / 256, 256, 0, stream>>>(hidden, W2, b2, out);
}

// Round 11
// 832.456 us; speedup vs baseline: 6.1746x; 1.3430x over previous
//
#include <hip/hip_runtime.h>
#include <hip/hip_bf16.h>

#define N_NODES 100000
#define N_EDGES 1600000
#define IN_DIM  128
#define HID     64
#define N_GRAPHS 500

// ============ CSR build ============
__global__ void zero_i(int* p, int n) {
    int i = blockIdx.x * blockDim.x + threadIdx.x;
    if (i < n) p[i] = 0;
}

__global__ void count_deg(const int* __restrict__ dst, int* __restrict__ counts, int E) {
    int e = blockIdx.x * blockDim.x + threadIdx.x;
    if (e < E) atomicAdd(&counts[dst[e]], 1);
}

// per-block exclusive scan of 256 elements + block total
__global__ void scan1(const int* __restrict__ counts, int* __restrict__ pre,
                      int* __restrict__ blockSums, int n) {
    __shared__ int tmp[256];
    int tid = threadIdx.x;
    int i = blockIdx.x * 256 + tid;
    int v = (i < n) ? counts[i] : 0;
    tmp[tid] = v; __syncthreads();
    int acc = v;
    for (int off = 1; off < 256; off <<= 1) {
        int add = (tid >= off) ? tmp[tid - off] : 0;
        __syncthreads();
        acc += add; tmp[tid] = acc;
        __syncthreads();
    }
    if (i < n) pre[i] = acc - v;
    if (tid == 255) blockSums[blockIdx.x] = acc;
}

// exclusive scan of <=512 block sums, in place (single block of 512)
__global__ void scan2(int* blockSums, int nb) {
    __shared__ int tmp[512];
    int tid = threadIdx.x;
    int v = (tid < nb) ? blockSums[tid] : 0;
    tmp[tid] = v; __syncthreads();
    int acc = v;
    for (int off = 1; off < 512; off <<= 1) {
        int add = (tid >= off) ? tmp[tid - off] : 0;
        __syncthreads();
        acc += add; tmp[tid] = acc;
        __syncthreads();
    }
    if (tid < nb) blockSums[tid] = acc - v;
}

__global__ void scan3(const int* __restrict__ pre, const int* __restrict__ blockSums,
                      int* __restrict__ row_start, int* __restrict__ cursor, int n, int E) {
    int i = blockIdx.x * blockDim.x + threadIdx.x;
    if (i < n) {
        int r = pre[i] + blockSums[i >> 8];
        row_start[i] = r;
        cursor[i] = r;
    } else if (i == n) {
        row_start[n] = E;
    }
}

// csr_src[p] = src of edge at CSR position p; csr_dst[p] = its dst
__global__ void csr_fill(const int* __restrict__ src, const int* __restrict__ dst,
                         int* __restrict__ cursor, int* __restrict__ csr_src,
                         int* __restrict__ csr_dst, int E) {
    int e = blockIdx.x * blockDim.x + threadIdx.x;
    if (e >= E) return;
    int d = dst[e];
    int p = atomicAdd(&cursor[d], 1);
    csr_src[p] = src[e];
    csr_dst[p] = d;
}

// ============ qkvs via tiled GEMM ============
template<int DIN>
__global__ __launch_bounds__(256) void qkvs_gemm(
    const float* __restrict__ x, int N,
    const float* __restrict__ Wq, const float* __restrict__ bq,
    const float* __restrict__ Wk, const float* __restrict__ bk,
    const float* __restrict__ Wv, const float* __restrict__ bv,
    const float* __restrict__ Ws, const float* __restrict__ bs,
    float* __restrict__ q, float* __restrict__ k,
    float* __restrict__ v, float* __restrict__ hout)
{
    constexpr int BM = 64, BK = 32;
    __shared__ float As[BK][BM + 1];   // x tile, transposed; +1 pad
    __shared__ float Bs[BK][64];       // W tile

    const int by = blockIdx.x;         // matrix id
    const float* W    = (by == 0) ? Wq : (by == 1) ? Wk : (by == 2) ? Wv : Ws;
    const float* bias = (by == 0) ? bq : (by == 1) ? bk : (by == 2) ? bv : bs;
    float*       outp = (by == 0) ? q  : (by == 1) ? k  : (by == 2) ? v  : hout;

    const int row0 = blockIdx.y * BM;
    const int tid  = threadIdx.x;
    const int tx   = (tid & 15) * 4;
    const int ty   = (tid >> 4) * 4;

    float acc[4][4] = {};

    for (int k0 = 0; k0 < DIN; k0 += BK) {
        #pragma unroll
        for (int h = 0; h < 2; ++h) {
            int idx = tid + h * 256;
            int r   = idx >> 3, c4 = idx & 7;
            int gr  = row0 + r;
            float4 val = (gr < N) ? *(const float4*)(x + (size_t)gr * DIN + k0 + c4 * 4)
                                  : make_float4(0.f, 0.f, 0.f, 0.f);
            int kk = c4 * 4;
            As[kk + 0][r] = val.x;
            As[kk + 1][r] = val.y;
            As[kk + 2][r] = val.z;
            As[kk + 3][r] = val.w;
        }
        #pragma unroll
        for (int h = 0; h < 2; ++h) {
            int kr = (tid >> 4) + h * 16;
            int n4 = (tid & 15) * 4;
            *(float4*)(&Bs[kr][n4]) = *(const float4*)(W + (size_t)(k0 + kr) * 64 + n4);
        }
        __syncthreads();

        #pragma unroll
        for (int kk = 0; kk < BK; ++kk) {
            float4 a = *(const float4*)(&As[kk][ty]);
            float4 b = *(const float4*)(&Bs[kk][tx]);
            acc[0][0] = fmaf(a.x, b.x, acc[0][0]);
            acc[0][1] = fmaf(a.x, b.y, acc[0][1]);
            acc[0][2] = fmaf(a.x, b.z, acc[0][2]);
            acc[0][3] = fmaf(a.x, b.w, acc[0][3]);
            acc[1][0] = fmaf(a.y, b.x, acc[1][0]);
            acc[1][1] = fmaf(a.y, b.y, acc[1][1]);
            acc[1][2] = fmaf(a.y, b.z, acc[1][2]);
            acc[1][3] = fmaf(a.y, b.w, acc[1][3]);
            acc[2][0] = fmaf(a.z, b.x, acc[2][0]);
            acc[2][1] = fmaf(a.z, b.y, acc[2][1]);
            acc[2][2] = fmaf(a.z, b.z, acc[2][2]);
            acc[2][3] = fmaf(a.z, b.w, acc[2][3]);
            acc[3][0] = fmaf(a.w, b.x, acc[3][0]);
            acc[3][1] = fmaf(a.w, b.y, acc[3][1]);
            acc[3][2] = fmaf(a.w, b.z, acc[3][2]);
            acc[3][3] = fmaf(a.w, b.w, acc[3][3]);
        }
        __syncthreads();
    }

    float4 bv4 = *(const float4*)(bias + tx);
    #pragma unroll
    for (int i = 0; i < 4; ++i) {
        int row = row0 + ty + i;
        if (row < N) {
            float4 o = make_float4(acc[i][0] + bv4.x, acc[i][1] + bv4.y,
                                   acc[i][2] + bv4.z, acc[i][3] + bv4.w);
            *(float4*)(outp + (size_t)row * 64 + tx) = o;
        }
    }
}

// ============ edge scores in CSR order ============
__global__ void edge_scores(const float* __restrict__ q, const float* __restrict__ k,
                            const int* __restrict__ csr_src, const int* __restrict__ csr_dst,
                            float* __restrict__ scores_csr, int E)
{
    int idx  = blockIdx.x * blockDim.x + threadIdx.x;
    int p    = idx >> 4;
    int lane = idx & 15;
    if (p >= E) return;
    int s = csr_src[p], d = csr_dst[p];
    float4 qv = ((const float4*)(q + (size_t)d * 64))[lane];
    float4 kv = ((const float4*)(k + (size_t)s * 64))[lane];
    float acc = qv.x * kv.x + qv.y * kv.y + qv.z * kv.z + qv.w * kv.w;
    acc += __shfl_xor(acc, 1);
    acc += __shfl_xor(acc, 2);
    acc += __shfl_xor(acc, 4);
    acc += __shfl_xor(acc, 8);
    if (lane == 0) scores_csr[p] = acc * 0.125f;  // / sqrt(64)
}

// ============ per-node softmax + aggregation + skip + relu ============
// Fast path (deg <= 64): scores & src held in registers, shfl-reduce softmax,
// shfl-broadcast gather with 4 loads in flight. No csr_exp traffic.
__global__ __launch_bounds__(256) void node_agg(
    const float* __restrict__ v, const float* __restrict__ scores_csr,
    const int* __restrict__ csr_src, const int* __restrict__ row_start,
    float* __restrict__ csr_exp, float* __restrict__ hout, int N)
{
    int node = blockIdx.x * 4 + (threadIdx.x >> 6);
    int lane = threadIdx.x & 63;
    if (node >= N) return;
    int start = row_start[node], end = row_start[node + 1];
    int deg = end - start;
    size_t o = (size_t)node * 64 + lane;

    if (deg == 0) { hout[o] = fmaxf(hout[o], 0.f); return; }

    float acc = 0.f;
    if (deg <= 64) {
        int   s_l = (lane < deg) ? csr_src[start + lane] : 0;
        float sc  = (lane < deg) ? scores_csr[start + lane] : -__builtin_inff();

        float m = sc;
        #pragma unroll
        for (int off = 1; off < 64; off <<= 1) m = fmaxf(m, __shfl_xor(m, off));

        float ex = expf(sc - m);          // lanes >= deg: exp(-inf)=0
        float ssum = ex;
        #pragma unroll
        for (int off = 1; off < 64; off <<= 1) ssum += __shfl_xor(ssum, off);
        float alpha = ex * (1.f / (ssum + 1e-16f));

        int j = 0;
        for (; j + 4 <= deg; j += 4) {
            float a0 = __shfl(alpha, j),     a1 = __shfl(alpha, j + 1);
            float a2 = __shfl(alpha, j + 2), a3 = __shfl(alpha, j + 3);
            int   s0 = __shfl(s_l, j),       s1 = __shfl(s_l, j + 1);
            int   s2 = __shfl(s_l, j + 2),   s3 = __shfl(s_l, j + 3);
            float v0 = v[(size_t)s0 * 64 + lane];
            float v1 = v[(size_t)s1 * 64 + lane];
            float v2 = v[(size_t)s2 * 64 + lane];
            float v3 = v[(size_t)s3 * 64 + lane];
            acc = fmaf(a0, v0, acc);
            acc = fmaf(a1, v1, acc);
            acc = fmaf(a2, v2, acc);
            acc = fmaf(a3, v3, acc);
        }
        for (; j < deg; ++j) {
            float a = __shfl(alpha, j);
            int   s = __shfl(s_l, j);
            acc = fmaf(a, v[(size_t)s * 64 + lane], acc);
        }
    } else {
        // rare fallback: strided softmax through csr_exp
        float m = -__builtin_inff();
        for (int j = start + lane; j < end; j += 64) m = fmaxf(m, scores_csr[j]);
        #pragma unroll
        for (int off = 1; off < 64; off <<= 1) m = fmaxf(m, __shfl_xor(m, off));

        float ssum = 0.f;
        for (int j = start + lane; j < end; j += 64) {
            float ex = expf(scores_csr[j] - m);
            csr_exp[j] = ex;
            ssum += ex;
        }
        #pragma unroll
        for (int off = 1; off < 64; off <<= 1) ssum += __shfl_xor(ssum, off);
        float inv = 1.f / (ssum + 1e-16f);

        for (int j = start; j < end; ++j) {
            int s   = csr_src[j];
            float a = csr_exp[j] * inv;
            acc = fmaf(a, v[(size_t)s * 64 + lane], acc);
        }
    }

    hout[o] = fmaxf(hout[o] + acc, 0.f);
}

// ============ pool + MLP ============
__global__ void zero_f(float* p, int n) {
    int i = blockIdx.x * blockDim.x + threadIdx.x;
    if (i < n) p[i] = 0.f;
}

__global__ void pool_kernel(const float* __restrict__ h, const int* __restrict__ batch,
                            float* __restrict__ pooled, int N)
{
    int col = threadIdx.x & 63;
    int rg  = threadIdx.x >> 6;
    int base = blockIdx.x * 128;
    int end  = base + 128; if (end > N) end = N;
    int gcur = -1; float acc = 0.f;
    for (int i = base + rg; i < end; i += 4) {
        int g = batch[i];
        if (g != gcur) {
            if (gcur >= 0) atomicAdd(&pooled[gcur * 64 + col], acc);
            gcur = g; acc = 0.f;
        }
        acc += h[(size_t)i * 64 + col];
    }
    if (gcur >= 0) atomicAdd(&pooled[gcur * 64 + col], acc);
}

__global__ void mlp1(const float* __restrict__ pooled, const float* __restrict__ W1,
                     const float* __restrict__ b1, float* __restrict__ hidden)
{
    int idx = blockIdx.x * blockDim.x + threadIdx.x;
    if (idx >= N_GRAPHS * 64) return;
    int g = idx >> 6, c = idx & 63;
    float acc = b1[c];
    for (int kk = 0; kk < 64; ++kk)
        acc = fmaf(pooled[g * 64 + kk], W1[kk * 64 + c], acc);
    hidden[idx] = fmaxf(acc, 0.f);
}

__global__ void mlp2(const float* __restrict__ hidden, const float* __restrict__ W2,
                     const float* __restrict__ b2, float* __restrict__ out)
{
    int idx = blockIdx.x * blockDim.x + threadIdx.x;
    if (idx >= N_GRAPHS * 16) return;
    int g = idx >> 4, c = idx & 15;
    float acc = b2[c];
    for (int kk = 0; kk < 64; ++kk)
        acc = fmaf(hidden[g * 64 + kk], W2[kk * 16 + c], acc);
    out[idx] = acc;
}

extern "C" void kernel_launch(void* const* d_in, const int* in_sizes, int n_in,
                              void* d_out, int out_size, void* d_ws, size_t ws_size,
                              hipStream_t stream)
{
    const float* x   = (const float*)d_in[0];
    const float* Wq0 = (const float*)d_in[1];  const float* bq0 = (const float*)d_in[2];
    const float* Wk0 = (const float*)d_in[3];  const float* bk0 = (const float*)d_in[4];
    const float* Wv0 = (const float*)d_in[5];  const float* bv0 = (const float*)d_in[6];
    const float* Ws0 = (const float*)d_in[7];  const float* bs0 = (const float*)d_in[8];
    const float* Wqs = (const float*)d_in[9];  const float* bqs = (const float*)d_in[10];
    const float* Wks = (const float*)d_in[11]; const float* bks = (const float*)d_in[12];
    const float* Wvs = (const float*)d_in[13]; const float* bvs = (const float*)d_in[14];
    const float* Wss = (const float*)d_in[15]; const float* bss = (const float*)d_in[16];
    const float* W1  = (const float*)d_in[17]; const float* b1  = (const float*)d_in[18];
    const float* W2  = (const float*)d_in[19]; const float* b2  = (const float*)d_in[20];
    const int*   ei  = (const int*)d_in[21];
    const int*   batch = (const int*)d_in[22];
    float* out = (float*)d_out;

    const int* src = ei;
    const int* dst = ei + N_EDGES;

    const size_t NH = (size_t)N_NODES * 64;
    float* q        = (float*)d_ws;
    float* k        = q + NH;
    float* v        = k + NH;
    float* hA       = v + NH;
    float* hB       = hA + NH;
    float* scores   = hB + NH;          // CSR order
    float* csr_exp  = scores + N_EDGES;
    int*   csr_src  = (int*)(csr_exp + N_EDGES);
    int*   csr_dst  = csr_src + N_EDGES;
    int*   row_start= csr_dst + N_EDGES;        // N_NODES+1
    int*   cursor   = row_start + N_NODES + 1;  // N_NODES
    int*   counts   = cursor + N_NODES;         // N_NODES
    int*   blockSums= counts + N_NODES;         // 512
    float* pooled   = (float*)(blockSums + 512);
    float* hidden   = pooled + N_GRAPHS * 64;

    struct LW { const float *Wq,*bq,*Wk,*bk,*Wv,*bv,*Ws,*bs; };
    LW lw[3] = {
        { Wq0, bq0, Wk0, bk0, Wv0, bv0, Ws0, bs0 },
        { Wqs, bqs, Wks, bks, Wvs, bvs, Wss, bss },
        { Wqs + 4096, bqs + 64, Wks + 4096, bks + 64, Wvs + 4096, bvs + 64, Wss + 4096, bss + 64 }
    };

    const int nodeBlocks   = (N_NODES + 255) / 256;
    const int edgeBlocks   = (N_EDGES + 255) / 256;
    const int edgeBlocks16 = (N_EDGES * 16 + 255) / 256;
    const int scanBlocks   = (N_NODES + 255) / 256;   // 391

    // ---- CSR build (once; edge_index constant across layers) ----
    zero_i<<<nodeBlocks, 256, 0, stream>>>(counts, N_NODES);
    count_deg<<<edgeBlocks, 256, 0, stream>>>(dst, counts, N_EDGES);
    scan1<<<scanBlocks, 256, 0, stream>>>(counts, counts, blockSums, N_NODES);
    scan2<<<1, 512, 0, stream>>>(blockSums, scanBlocks);
    scan3<<<(N_NODES + 256) / 256, 256, 0, stream>>>(counts, blockSums, row_start, cursor,
                                                     N_NODES, N_EDGES);
    csr_fill<<<edgeBlocks, 256, 0, stream>>>(src, dst, cursor, csr_src, csr_dst, N_EDGES);

    // ---- 3 TransformerConv layers ----
    const dim3 gemmGrid(4, (N_NODES + 63) / 64);
    for (int L = 0; L < 3; ++L) {
        if (L == 0) {
            qkvs_gemm<IN_DIM><<<gemmGrid, 256, 0, stream>>>(x, N_NODES,
                lw[0].Wq, lw[0].bq, lw[0].Wk, lw[0].bk, lw[0].Wv, lw[0].bv, lw[0].Ws, lw[0].bs,
                q, k, v, hA);
        } else {
            const float* hin = (L == 1) ? hA : hB;
            float* hou       = (L == 1) ? hB : hA;
            qkvs_gemm<HID><<<gemmGrid, 256, 0, stream>>>(hin, N_NODES,
                lw[L].Wq, lw[L].bq, lw[L].Wk, lw[L].bk, lw[L].Wv, lw[L].bv, lw[L].Ws, lw[L].bs,
                q, k, v, hou);
        }
        float* hou = (L == 0) ? hA : ((L == 1) ? hB : hA);
        edge_scores<<<edgeBlocks16, 256, 0, stream>>>(q, k, csr_src, csr_dst, scores, N_EDGES);
        node_agg<<<(N_NODES + 3) / 4, 256, 0, stream>>>(v, scores, csr_src, row_start,
                                                        csr_exp, hou, N_NODES);
    }

    // ---- pool + MLP ----
    zero_f<<<(N_GRAPHS * 64 + 255) / 256, 256, 0, stream>>>(pooled, N_GRAPHS * 64);
    pool_kernel<<<(N_NODES + 127) / 128, 256, 0, stream>>>(hA, batch, pooled, N_NODES);
    mlp1<<<(N_GRAPHS * 64 + 255) / 256, 256, 0, stream>>>(pooled, W1, b1, hidden);
    mlp2<<<(N_GRAPHS * 16 + 255) / 256, 256, 0, stream>>>(hidden, W2, b2, out);
}

// Round 12
// 832.274 us; speedup vs baseline: 6.1760x; 1.0002x over previous
//
#include <hip/hip_runtime.h>
#include <hip/hip_bf16.h>

#define N_NODES 100000
#define N_EDGES 1600000
#define IN_DIM  128
#define HID     64
#define N_GRAPHS 500

// ============ CSR build ============
__global__ void zero_i(int* p, int n) {
    int i = blockIdx.x * blockDim.x + threadIdx.x;
    if (i < n) p[i] = 0;
}

__global__ void count_deg(const int* __restrict__ dst, int* __restrict__ counts, int E) {
    int e = blockIdx.x * blockDim.x + threadIdx.x;
    if (e < E) atomicAdd(&counts[dst[e]], 1);
}

// per-block exclusive scan of 256 elements + block total
__global__ void scan1(const int* __restrict__ counts, int* __restrict__ pre,
                      int* __restrict__ blockSums, int n) {
    __shared__ int tmp[256];
    int tid = threadIdx.x;
    int i = blockIdx.x * 256 + tid;
    int v = (i < n) ? counts[i] : 0;
    tmp[tid] = v; __syncthreads();
    int acc = v;
    for (int off = 1; off < 256; off <<= 1) {
        int add = (tid >= off) ? tmp[tid - off] : 0;
        __syncthreads();
        acc += add; tmp[tid] = acc;
        __syncthreads();
    }
    if (i < n) pre[i] = acc - v;
    if (tid == 255) blockSums[blockIdx.x] = acc;
}

// exclusive scan of <=512 block sums, in place (single block of 512)
__global__ void scan2(int* blockSums, int nb) {
    __shared__ int tmp[512];
    int tid = threadIdx.x;
    int v = (tid < nb) ? blockSums[tid] : 0;
    tmp[tid] = v; __syncthreads();
    int acc = v;
    for (int off = 1; off < 512; off <<= 1) {
        int add = (tid >= off) ? tmp[tid - off] : 0;
        __syncthreads();
        acc += add; tmp[tid] = acc;
        __syncthreads();
    }
    if (tid < nb) blockSums[tid] = acc - v;
}

__global__ void scan3(const int* __restrict__ pre, const int* __restrict__ blockSums,
                      int* __restrict__ row_start, int* __restrict__ cursor, int n, int E) {
    int i = blockIdx.x * blockDim.x + threadIdx.x;
    if (i < n) {
        int r = pre[i] + blockSums[i >> 8];
        row_start[i] = r;
        cursor[i] = r;
    } else if (i == n) {
        row_start[n] = E;
    }
}

// csr_sd[p] = {src, dst} of edge at CSR position p — single 8B scattered store
__global__ void csr_fill(const int* __restrict__ src, const int* __restrict__ dst,
                         int* __restrict__ cursor, int2* __restrict__ csr_sd, int E) {
    int e = blockIdx.x * blockDim.x + threadIdx.x;
    if (e >= E) return;
    int d = dst[e];
    int p = atomicAdd(&cursor[d], 1);
    csr_sd[p] = make_int2(src[e], d);
}

// ============ qkvs via tiled GEMM ============
template<int DIN>
__global__ __launch_bounds__(256) void qkvs_gemm(
    const float* __restrict__ x, int N,
    const float* __restrict__ Wq, const float* __restrict__ bq,
    const float* __restrict__ Wk, const float* __restrict__ bk,
    const float* __restrict__ Wv, const float* __restrict__ bv,
    const float* __restrict__ Ws, const float* __restrict__ bs,
    float* __restrict__ q, float* __restrict__ k,
    float* __restrict__ v, float* __restrict__ hout)
{
    constexpr int BM = 64, BK = 32;
    __shared__ float As[BK][BM + 1];   // x tile, transposed; +1 pad
    __shared__ float Bs[BK][64];       // W tile

    const int by = blockIdx.x;         // matrix id
    const float* W    = (by == 0) ? Wq : (by == 1) ? Wk : (by == 2) ? Wv : Ws;
    const float* bias = (by == 0) ? bq : (by == 1) ? bk : (by == 2) ? bv : bs;
    float*       outp = (by == 0) ? q  : (by == 1) ? k  : (by == 2) ? v  : hout;

    const int row0 = blockIdx.y * BM;
    const int tid  = threadIdx.x;
    const int tx   = (tid & 15) * 4;
    const int ty   = (tid >> 4) * 4;

    float acc[4][4] = {};

    for (int k0 = 0; k0 < DIN; k0 += BK) {
        #pragma unroll
        for (int h = 0; h < 2; ++h) {
            int idx = tid + h * 256;
            int r   = idx >> 3, c4 = idx & 7;
            int gr  = row0 + r;
            float4 val = (gr < N) ? *(const float4*)(x + (size_t)gr * DIN + k0 + c4 * 4)
                                  : make_float4(0.f, 0.f, 0.f, 0.f);
            int kk = c4 * 4;
            As[kk + 0][r] = val.x;
            As[kk + 1][r] = val.y;
            As[kk + 2][r] = val.z;
            As[kk + 3][r] = val.w;
        }
        #pragma unroll
        for (int h = 0; h < 2; ++h) {
            int kr = (tid >> 4) + h * 16;
            int n4 = (tid & 15) * 4;
            *(float4*)(&Bs[kr][n4]) = *(const float4*)(W + (size_t)(k0 + kr) * 64 + n4);
        }
        __syncthreads();

        #pragma unroll
        for (int kk = 0; kk < BK; ++kk) {
            float4 a = *(const float4*)(&As[kk][ty]);
            float4 b = *(const float4*)(&Bs[kk][tx]);
            acc[0][0] = fmaf(a.x, b.x, acc[0][0]);
            acc[0][1] = fmaf(a.x, b.y, acc[0][1]);
            acc[0][2] = fmaf(a.x, b.z, acc[0][2]);
            acc[0][3] = fmaf(a.x, b.w, acc[0][3]);
            acc[1][0] = fmaf(a.y, b.x, acc[1][0]);
            acc[1][1] = fmaf(a.y, b.y, acc[1][1]);
            acc[1][2] = fmaf(a.y, b.z, acc[1][2]);
            acc[1][3] = fmaf(a.y, b.w, acc[1][3]);
            acc[2][0] = fmaf(a.z, b.x, acc[2][0]);
            acc[2][1] = fmaf(a.z, b.y, acc[2][1]);
            acc[2][2] = fmaf(a.z, b.z, acc[2][2]);
            acc[2][3] = fmaf(a.z, b.w, acc[2][3]);
            acc[3][0] = fmaf(a.w, b.x, acc[3][0]);
            acc[3][1] = fmaf(a.w, b.y, acc[3][1]);
            acc[3][2] = fmaf(a.w, b.z, acc[3][2]);
            acc[3][3] = fmaf(a.w, b.w, acc[3][3]);
        }
        __syncthreads();
    }

    float4 bv4 = *(const float4*)(bias + tx);
    #pragma unroll
    for (int i = 0; i < 4; ++i) {
        int row = row0 + ty + i;
        if (row < N) {
            float4 o = make_float4(acc[i][0] + bv4.x, acc[i][1] + bv4.y,
                                   acc[i][2] + bv4.z, acc[i][3] + bv4.w);
            *(float4*)(outp + (size_t)row * 64 + tx) = o;
        }
    }
}

// ============ edge scores in CSR order ============
__global__ void edge_scores(const float* __restrict__ q, const float* __restrict__ k,
                            const int2* __restrict__ csr_sd,
                            float* __restrict__ scores_csr, int E)
{
    int idx  = blockIdx.x * blockDim.x + threadIdx.x;
    int p    = idx >> 4;
    int lane = idx & 15;
    if (p >= E) return;
    int2 sd = csr_sd[p];
    float4 qv = ((const float4*)(q + (size_t)sd.y * 64))[lane];
    float4 kv = ((const float4*)(k + (size_t)sd.x * 64))[lane];
    float acc = qv.x * kv.x + qv.y * kv.y + qv.z * kv.z + qv.w * kv.w;
    acc += __shfl_xor(acc, 1);
    acc += __shfl_xor(acc, 2);
    acc += __shfl_xor(acc, 4);
    acc += __shfl_xor(acc, 8);
    if (lane == 0) scores_csr[p] = acc * 0.125f;  // / sqrt(64)
}

// ============ per-node softmax + aggregation + skip + relu ============
__global__ __launch_bounds__(256) void node_agg(
    const float* __restrict__ v, const float* __restrict__ scores_csr,
    const int2* __restrict__ csr_sd, const int* __restrict__ row_start,
    float* __restrict__ csr_exp, float* __restrict__ hout, int N)
{
    int node = blockIdx.x * 4 + (threadIdx.x >> 6);
    int lane = threadIdx.x & 63;
    if (node >= N) return;
    int start = row_start[node], end = row_start[node + 1];
    int deg = end - start;
    size_t o = (size_t)node * 64 + lane;

    if (deg == 0) { hout[o] = fmaxf(hout[o], 0.f); return; }

    float acc = 0.f;
    if (deg <= 64) {
        int   s_l = (lane < deg) ? csr_sd[start + lane].x : 0;
        float sc  = (lane < deg) ? scores_csr[start + lane] : -__builtin_inff();

        float m = sc;
        #pragma unroll
        for (int off = 1; off < 64; off <<= 1) m = fmaxf(m, __shfl_xor(m, off));

        float ex = expf(sc - m);          // lanes >= deg: exp(-inf)=0
        float ssum = ex;
        #pragma unroll
        for (int off = 1; off < 64; off <<= 1) ssum += __shfl_xor(ssum, off);
        float alpha = ex * (1.f / (ssum + 1e-16f));

        int j = 0;
        for (; j + 4 <= deg; j += 4) {
            float a0 = __shfl(alpha, j),     a1 = __shfl(alpha, j + 1);
            float a2 = __shfl(alpha, j + 2), a3 = __shfl(alpha, j + 3);
            int   s0 = __shfl(s_l, j),       s1 = __shfl(s_l, j + 1);
            int   s2 = __shfl(s_l, j + 2),   s3 = __shfl(s_l, j + 3);
            float v0 = v[(size_t)s0 * 64 + lane];
            float v1 = v[(size_t)s1 * 64 + lane];
            float v2 = v[(size_t)s2 * 64 + lane];
            float v3 = v[(size_t)s3 * 64 + lane];
            acc = fmaf(a0, v0, acc);
            acc = fmaf(a1, v1, acc);
            acc = fmaf(a2, v2, acc);
            acc = fmaf(a3, v3, acc);
        }
        for (; j < deg; ++j) {
            float a = __shfl(alpha, j);
            int   s = __shfl(s_l, j);
            acc = fmaf(a, v[(size_t)s * 64 + lane], acc);
        }
    } else {
        // rare fallback: strided softmax through csr_exp
        float m = -__builtin_inff();
        for (int j = start + lane; j < end; j += 64) m = fmaxf(m, scores_csr[j]);
        #pragma unroll
        for (int off = 1; off < 64; off <<= 1) m = fmaxf(m, __shfl_xor(m, off));

        float ssum = 0.f;
        for (int j = start + lane; j < end; j += 64) {
            float ex = expf(scores_csr[j] - m);
            csr_exp[j] = ex;
            ssum += ex;
        }
        #pragma unroll
        for (int off = 1; off < 64; off <<= 1) ssum += __shfl_xor(ssum, off);
        float inv = 1.f / (ssum + 1e-16f);

        for (int j = start; j < end; ++j) {
            int s   = csr_sd[j].x;
            float a = csr_exp[j] * inv;
            acc = fmaf(a, v[(size_t)s * 64 + lane], acc);
        }
    }

    hout[o] = fmaxf(hout[o] + acc, 0.f);
}

// ============ pool + MLP ============
__global__ void zero_f(float* p, int n) {
    int i = blockIdx.x * blockDim.x + threadIdx.x;
    if (i < n) p[i] = 0.f;
}

__global__ void pool_kernel(const float* __restrict__ h, const int* __restrict__ batch,
                            float* __restrict__ pooled, int N)
{
    int col = threadIdx.x & 63;
    int rg  = threadIdx.x >> 6;
    int base = blockIdx.x * 128;
    int end  = base + 128; if (end > N) end = N;
    int gcur = -1; float acc = 0.f;
    for (int i = base + rg; i < end; i += 4) {
        int g = batch[i];
        if (g != gcur) {
            if (gcur >= 0) atomicAdd(&pooled[gcur * 64 + col], acc);
            gcur = g; acc = 0.f;
        }
        acc += h[(size_t)i * 64 + col];
    }
    if (gcur >= 0) atomicAdd(&pooled[gcur * 64 + col], acc);
}

__global__ void mlp1(const float* __restrict__ pooled, const float* __restrict__ W1,
                     const float* __restrict__ b1, float* __restrict__ hidden)
{
    int idx = blockIdx.x * blockDim.x + threadIdx.x;
    if (idx >= N_GRAPHS * 64) return;
    int g = idx >> 6, c = idx & 63;
    float acc = b1[c];
    for (int kk = 0; kk < 64; ++kk)
        acc = fmaf(pooled[g * 64 + kk], W1[kk * 64 + c], acc);
    hidden[idx] = fmaxf(acc, 0.f);
}

__global__ void mlp2(const float* __restrict__ hidden, const float* __restrict__ W2,
                     const float* __restrict__ b2, float* __restrict__ out)
{
    int idx = blockIdx.x * blockDim.x + threadIdx.x;
    if (idx >= N_GRAPHS * 16) return;
    int g = idx >> 4, c = idx & 15;
    float acc = b2[c];
    for (int kk = 0; kk < 64; ++kk)
        acc = fmaf(hidden[g * 64 + kk], W2[kk * 16 + c], acc);
    out[idx] = acc;
}

extern "C" void kernel_launch(void* const* d_in, const int* in_sizes, int n_in,
                              void* d_out, int out_size, void* d_ws, size_t ws_size,
                              hipStream_t stream)
{
    const float* x   = (const float*)d_in[0];
    const float* Wq0 = (const float*)d_in[1];  const float* bq0 = (const float*)d_in[2];
    const float* Wk0 = (const float*)d_in[3];  const float* bk0 = (const float*)d_in[4];
    const float* Wv0 = (const float*)d_in[5];  const float* bv0 = (const float*)d_in[6];
    const float* Ws0 = (const float*)d_in[7];  const float* bs0 = (const float*)d_in[8];
    const float* Wqs = (const float*)d_in[9];  const float* bqs = (const float*)d_in[10];
    const float* Wks = (const float*)d_in[11]; const float* bks = (const float*)d_in[12];
    const float* Wvs = (const float*)d_in[13]; const float* bvs = (const float*)d_in[14];
    const float* Wss = (const float*)d_in[15]; const float* bss = (const float*)d_in[16];
    const float* W1  = (const float*)d_in[17]; const float* b1  = (const float*)d_in[18];
    const float* W2  = (const float*)d_in[19]; const float* b2  = (const float*)d_in[20];
    const int*   ei  = (const int*)d_in[21];
    const int*   batch = (const int*)d_in[22];
    float* out = (float*)d_out;

    const int* src = ei;
    const int* dst = ei + N_EDGES;

    const size_t NH = (size_t)N_NODES * 64;
    float* q        = (float*)d_ws;
    float* k        = q + NH;
    float* v        = k + NH;
    float* hA       = v + NH;
    float* hB       = hA + NH;
    float* scores   = hB + NH;          // CSR order
    float* csr_exp  = scores + N_EDGES;
    int2*  csr_sd   = (int2*)(csr_exp + N_EDGES);   // 2*N_EDGES ints
    int*   row_start= (int*)(csr_sd + N_EDGES);     // N_NODES+1
    int*   cursor   = row_start + N_NODES + 1;      // N_NODES
    int*   counts   = cursor + N_NODES;             // N_NODES
    int*   blockSums= counts + N_NODES;             // 512
    float* pooled   = (float*)(blockSums + 512);
    float* hidden   = pooled + N_GRAPHS * 64;

    struct LW { const float *Wq,*bq,*Wk,*bk,*Wv,*bv,*Ws,*bs; };
    LW lw[3] = {
        { Wq0, bq0, Wk0, bk0, Wv0, bv0, Ws0, bs0 },
        { Wqs, bqs, Wks, bks, Wvs, bvs, Wss, bss },
        { Wqs + 4096, bqs + 64, Wks + 4096, bks + 64, Wvs + 4096, bvs + 64, Wss + 4096, bss + 64 }
    };

    const int nodeBlocks   = (N_NODES + 255) / 256;
    const int edgeBlocks   = (N_EDGES + 255) / 256;
    const int edgeBlocks16 = (N_EDGES * 16 + 255) / 256;
    const int scanBlocks   = (N_NODES + 255) / 256;   // 391

    // ---- CSR build (once; edge_index constant across layers) ----
    zero_i<<<nodeBlocks, 256, 0, stream>>>(counts, N_NODES);
    count_deg<<<edgeBlocks, 256, 0, stream>>>(dst, counts, N_EDGES);
    scan1<<<scanBlocks, 256, 0, stream>>>(counts, counts, blockSums, N_NODES);
    scan2<<<1, 512, 0, stream>>>(blockSums, scanBlocks);
    scan3<<<(N_NODES + 256) / 256, 256, 0, stream>>>(counts, blockSums, row_start, cursor,
                                                     N_NODES, N_EDGES);
    csr_fill<<<edgeBlocks, 256, 0, stream>>>(src, dst, cursor, csr_sd, N_EDGES);

    // ---- 3 TransformerConv layers ----
    const dim3 gemmGrid(4, (N_NODES + 63) / 64);
    for (int L = 0; L < 3; ++L) {
        if (L == 0) {
            qkvs_gemm<IN_DIM><<<gemmGrid, 256, 0, stream>>>(x, N_NODES,
                lw[0].Wq, lw[0].bq, lw[0].Wk, lw[0].bk, lw[0].Wv, lw[0].bv, lw[0].Ws, lw[0].bs,
                q, k, v, hA);
        } else {
            const float* hin = (L == 1) ? hA : hB;
            float* hou       = (L == 1) ? hB : hA;
            qkvs_gemm<HID><<<gemmGrid, 256, 0, stream>>>(hin, N_NODES,
                lw[L].Wq, lw[L].bq, lw[L].Wk, lw[L].bk, lw[L].Wv, lw[L].bv, lw[L].Ws, lw[L].bs,
                q, k, v, hou);
        }
        float* hou = (L == 0) ? hA : ((L == 1) ? hB : hA);
        edge_scores<<<edgeBlocks16, 256, 0, stream>>>(q, k, csr_sd, scores, N_EDGES);
        node_agg<<<(N_NODES + 3) / 4, 256, 0, stream>>>(v, scores, csr_sd, row_start,
                                                        csr_exp, hou, N_NODES);
    }

    // ---- pool + MLP ----
    zero_f<<<(N_GRAPHS * 64 + 255) / 256, 256, 0, stream>>>(pooled, N_GRAPHS * 64);
    pool_kernel<<<(N_NODES + 127) / 128, 256, 0, stream>>>(hA, batch, pooled, N_NODES);
    mlp1<<<(N_GRAPHS * 64 + 255) / 256, 256, 0, stream>>>(pooled, W1, b1, hidden);
    mlp2<<<(N_GRAPHS * 16 + 255) / 256, 256, 0, stream>>>(hidden, W2, b2, out);
}

// Round 13
// 802.270 us; speedup vs baseline: 6.4070x; 1.0374x over previous
//
#include <hip/hip_runtime.h>
#include <hip/hip_bf16.h>

#define N_NODES 100000
#define N_EDGES 1600000
#define IN_DIM  128
#define HID     64
#define N_GRAPHS 500

// bf16 helpers (RNE pack, shift unpack)
__device__ inline unsigned short f2bf(float f) {
    unsigned u = __float_as_uint(f);
    u += 0x7FFFu + ((u >> 16) & 1u);
    return (unsigned short)(u >> 16);
}
__device__ inline float bf2f(unsigned short b) {
    return __uint_as_float(((unsigned)b) << 16);
}

// ============ CSR build ============
__global__ void zero_i(int* p, int n) {
    int i = blockIdx.x * blockDim.x + threadIdx.x;
    if (i < n) p[i] = 0;
}

__global__ void count_deg(const int* __restrict__ dst, int* __restrict__ counts, int E) {
    int e = blockIdx.x * blockDim.x + threadIdx.x;
    if (e < E) atomicAdd(&counts[dst[e]], 1);
}

__global__ void scan1(const int* __restrict__ counts, int* __restrict__ pre,
                      int* __restrict__ blockSums, int n) {
    __shared__ int tmp[256];
    int tid = threadIdx.x;
    int i = blockIdx.x * 256 + tid;
    int v = (i < n) ? counts[i] : 0;
    tmp[tid] = v; __syncthreads();
    int acc = v;
    for (int off = 1; off < 256; off <<= 1) {
        int add = (tid >= off) ? tmp[tid - off] : 0;
        __syncthreads();
        acc += add; tmp[tid] = acc;
        __syncthreads();
    }
    if (i < n) pre[i] = acc - v;
    if (tid == 255) blockSums[blockIdx.x] = acc;
}

__global__ void scan2(int* blockSums, int nb) {
    __shared__ int tmp[512];
    int tid = threadIdx.x;
    int v = (tid < nb) ? blockSums[tid] : 0;
    tmp[tid] = v; __syncthreads();
    int acc = v;
    for (int off = 1; off < 512; off <<= 1) {
        int add = (tid >= off) ? tmp[tid - off] : 0;
        __syncthreads();
        acc += add; tmp[tid] = acc;
        __syncthreads();
    }
    if (tid < nb) blockSums[tid] = acc - v;
}

__global__ void scan3(const int* __restrict__ pre, const int* __restrict__ blockSums,
                      int* __restrict__ row_start, int* __restrict__ cursor, int n, int E) {
    int i = blockIdx.x * blockDim.x + threadIdx.x;
    if (i < n) {
        int r = pre[i] + blockSums[i >> 8];
        row_start[i] = r;
        cursor[i] = r;
    } else if (i == n) {
        row_start[n] = E;
    }
}

__global__ void csr_fill(const int* __restrict__ src, const int* __restrict__ dst,
                         int* __restrict__ cursor, int2* __restrict__ csr_sd, int E) {
    int e = blockIdx.x * blockDim.x + threadIdx.x;
    if (e >= E) return;
    int d = dst[e];
    int p = atomicAdd(&cursor[d], 1);
    csr_sd[p] = make_int2(src[e], d);
}

// ============ qkvs via tiled GEMM (k,v emitted as bf16; q,skip fp32) ============
template<int DIN>
__global__ __launch_bounds__(256) void qkvs_gemm(
    const float* __restrict__ x, int N,
    const float* __restrict__ Wq, const float* __restrict__ bq,
    const float* __restrict__ Wk, const float* __restrict__ bk,
    const float* __restrict__ Wv, const float* __restrict__ bv,
    const float* __restrict__ Ws, const float* __restrict__ bs,
    float* __restrict__ q, unsigned short* __restrict__ kb,
    unsigned short* __restrict__ vb, float* __restrict__ hout)
{
    constexpr int BM = 64, BK = 32;
    __shared__ float As[BK][BM + 1];
    __shared__ float Bs[BK][64];

    const int by = blockIdx.x;         // matrix id
    const float* W    = (by == 0) ? Wq : (by == 1) ? Wk : (by == 2) ? Wv : Ws;
    const float* bias = (by == 0) ? bq : (by == 1) ? bk : (by == 2) ? bv : bs;

    const int row0 = blockIdx.y * BM;
    const int tid  = threadIdx.x;
    const int tx   = (tid & 15) * 4;
    const int ty   = (tid >> 4) * 4;

    float acc[4][4] = {};

    for (int k0 = 0; k0 < DIN; k0 += BK) {
        #pragma unroll
        for (int h = 0; h < 2; ++h) {
            int idx = tid + h * 256;
            int r   = idx >> 3, c4 = idx & 7;
            int gr  = row0 + r;
            float4 val = (gr < N) ? *(const float4*)(x + (size_t)gr * DIN + k0 + c4 * 4)
                                  : make_float4(0.f, 0.f, 0.f, 0.f);
            int kk = c4 * 4;
            As[kk + 0][r] = val.x;
            As[kk + 1][r] = val.y;
            As[kk + 2][r] = val.z;
            As[kk + 3][r] = val.w;
        }
        #pragma unroll
        for (int h = 0; h < 2; ++h) {
            int kr = (tid >> 4) + h * 16;
            int n4 = (tid & 15) * 4;
            *(float4*)(&Bs[kr][n4]) = *(const float4*)(W + (size_t)(k0 + kr) * 64 + n4);
        }
        __syncthreads();

        #pragma unroll
        for (int kk = 0; kk < BK; ++kk) {
            float4 a = *(const float4*)(&As[kk][ty]);
            float4 b = *(const float4*)(&Bs[kk][tx]);
            acc[0][0] = fmaf(a.x, b.x, acc[0][0]);
            acc[0][1] = fmaf(a.x, b.y, acc[0][1]);
            acc[0][2] = fmaf(a.x, b.z, acc[0][2]);
            acc[0][3] = fmaf(a.x, b.w, acc[0][3]);
            acc[1][0] = fmaf(a.y, b.x, acc[1][0]);
            acc[1][1] = fmaf(a.y, b.y, acc[1][1]);
            acc[1][2] = fmaf(a.y, b.z, acc[1][2]);
            acc[1][3] = fmaf(a.y, b.w, acc[1][3]);
            acc[2][0] = fmaf(a.z, b.x, acc[2][0]);
            acc[2][1] = fmaf(a.z, b.y, acc[2][1]);
            acc[2][2] = fmaf(a.z, b.z, acc[2][2]);
            acc[2][3] = fmaf(a.z, b.w, acc[2][3]);
            acc[3][0] = fmaf(a.w, b.x, acc[3][0]);
            acc[3][1] = fmaf(a.w, b.y, acc[3][1]);
            acc[3][2] = fmaf(a.w, b.z, acc[3][2]);
            acc[3][3] = fmaf(a.w, b.w, acc[3][3]);
        }
        __syncthreads();
    }

    float4 bv4 = *(const float4*)(bias + tx);
    if (by == 1 || by == 2) {
        unsigned short* op = (by == 1) ? kb : vb;
        #pragma unroll
        for (int i = 0; i < 4; ++i) {
            int row = row0 + ty + i;
            if (row < N) {
                ushort4 pk;
                pk.x = f2bf(acc[i][0] + bv4.x);
                pk.y = f2bf(acc[i][1] + bv4.y);
                pk.z = f2bf(acc[i][2] + bv4.z);
                pk.w = f2bf(acc[i][3] + bv4.w);
                *(ushort4*)(op + (size_t)row * 64 + tx) = pk;
            }
        }
    } else {
        float* op = (by == 0) ? q : hout;
        #pragma unroll
        for (int i = 0; i < 4; ++i) {
            int row = row0 + ty + i;
            if (row < N) {
                float4 o = make_float4(acc[i][0] + bv4.x, acc[i][1] + bv4.y,
                                       acc[i][2] + bv4.z, acc[i][3] + bv4.w);
                *(float4*)(op + (size_t)row * 64 + tx) = o;
            }
        }
    }
}

// ============ edge scores in CSR order (k in bf16) ============
__global__ void edge_scores(const float* __restrict__ q, const unsigned short* __restrict__ kb,
                            const int2* __restrict__ csr_sd,
                            float* __restrict__ scores_csr, int E)
{
    int idx  = blockIdx.x * blockDim.x + threadIdx.x;
    int p    = idx >> 4;
    int lane = idx & 15;
    if (p >= E) return;
    int2 sd = csr_sd[p];
    float4  qv = ((const float4*)(q + (size_t)sd.y * 64))[lane];
    ushort4 kv = ((const ushort4*)(kb + (size_t)sd.x * 64))[lane];
    float acc = qv.x * bf2f(kv.x) + qv.y * bf2f(kv.y)
              + qv.z * bf2f(kv.z) + qv.w * bf2f(kv.w);
    acc += __shfl_xor(acc, 1);
    acc += __shfl_xor(acc, 2);
    acc += __shfl_xor(acc, 4);
    acc += __shfl_xor(acc, 8);
    if (lane == 0) scores_csr[p] = acc * 0.125f;  // / sqrt(64)
}

// ============ per-node softmax + aggregation + skip + relu (v in bf16) ============
__global__ __launch_bounds__(256) void node_agg(
    const unsigned short* __restrict__ vb, const float* __restrict__ scores_csr,
    const int2* __restrict__ csr_sd, const int* __restrict__ row_start,
    float* __restrict__ csr_exp, float* __restrict__ hout, int N)
{
    int node = blockIdx.x * 4 + (threadIdx.x >> 6);
    int lane = threadIdx.x & 63;
    if (node >= N) return;
    int start = row_start[node], end = row_start[node + 1];
    int deg = end - start;
    size_t o = (size_t)node * 64 + lane;

    if (deg == 0) { hout[o] = fmaxf(hout[o], 0.f); return; }

    float acc = 0.f;
    if (deg <= 64) {
        int   s_l = (lane < deg) ? csr_sd[start + lane].x : 0;
        float sc  = (lane < deg) ? scores_csr[start + lane] : -__builtin_inff();

        float m = sc;
        #pragma unroll
        for (int off = 1; off < 64; off <<= 1) m = fmaxf(m, __shfl_xor(m, off));

        float ex = expf(sc - m);
        float ssum = ex;
        #pragma unroll
        for (int off = 1; off < 64; off <<= 1) ssum += __shfl_xor(ssum, off);
        float alpha = ex * (1.f / (ssum + 1e-16f));

        int j = 0;
        for (; j + 4 <= deg; j += 4) {
            float a0 = __shfl(alpha, j),     a1 = __shfl(alpha, j + 1);
            float a2 = __shfl(alpha, j + 2), a3 = __shfl(alpha, j + 3);
            int   s0 = __shfl(s_l, j),       s1 = __shfl(s_l, j + 1);
            int   s2 = __shfl(s_l, j + 2),   s3 = __shfl(s_l, j + 3);
            float v0 = bf2f(vb[(size_t)s0 * 64 + lane]);
            float v1 = bf2f(vb[(size_t)s1 * 64 + lane]);
            float v2 = bf2f(vb[(size_t)s2 * 64 + lane]);
            float v3 = bf2f(vb[(size_t)s3 * 64 + lane]);
            acc = fmaf(a0, v0, acc);
            acc = fmaf(a1, v1, acc);
            acc = fmaf(a2, v2, acc);
            acc = fmaf(a3, v3, acc);
        }
        for (; j < deg; ++j) {
            float a = __shfl(alpha, j);
            int   s = __shfl(s_l, j);
            acc = fmaf(a, bf2f(vb[(size_t)s * 64 + lane]), acc);
        }
    } else {
        float m = -__builtin_inff();
        for (int j = start + lane; j < end; j += 64) m = fmaxf(m, scores_csr[j]);
        #pragma unroll
        for (int off = 1; off < 64; off <<= 1) m = fmaxf(m, __shfl_xor(m, off));

        float ssum = 0.f;
        for (int j = start + lane; j < end; j += 64) {
            float ex = expf(scores_csr[j] - m);
            csr_exp[j] = ex;
            ssum += ex;
        }
        #pragma unroll
        for (int off = 1; off < 64; off <<= 1) ssum += __shfl_xor(ssum, off);
        float inv = 1.f / (ssum + 1e-16f);

        for (int j = start; j < end; ++j) {
            int s   = csr_sd[j].x;
            float a = csr_exp[j] * inv;
            acc = fmaf(a, bf2f(vb[(size_t)s * 64 + lane]), acc);
        }
    }

    hout[o] = fmaxf(hout[o] + acc, 0.f);
}

// ============ pool + MLP ============
__global__ void zero_f(float* p, int n) {
    int i = blockIdx.x * blockDim.x + threadIdx.x;
    if (i < n) p[i] = 0.f;
}

__global__ void pool_kernel(const float* __restrict__ h, const int* __restrict__ batch,
                            float* __restrict__ pooled, int N)
{
    int col = threadIdx.x & 63;
    int rg  = threadIdx.x >> 6;
    int base = blockIdx.x * 128;
    int end  = base + 128; if (end > N) end = N;
    int gcur = -1; float acc = 0.f;
    for (int i = base + rg; i < end; i += 4) {
        int g = batch[i];
        if (g != gcur) {
            if (gcur >= 0) atomicAdd(&pooled[gcur * 64 + col], acc);
            gcur = g; acc = 0.f;
        }
        acc += h[(size_t)i * 64 + col];
    }
    if (gcur >= 0) atomicAdd(&pooled[gcur * 64 + col], acc);
}

__global__ void mlp1(const float* __restrict__ pooled, const float* __restrict__ W1,
                     const float* __restrict__ b1, float* __restrict__ hidden)
{
    int idx = blockIdx.x * blockDim.x + threadIdx.x;
    if (idx >= N_GRAPHS * 64) return;
    int g = idx >> 6, c = idx & 63;
    float acc = b1[c];
    for (int kk = 0; kk < 64; ++kk)
        acc = fmaf(pooled[g * 64 + kk], W1[kk * 64 + c], acc);
    hidden[idx] = fmaxf(acc, 0.f);
}

__global__ void mlp2(const float* __restrict__ hidden, const float* __restrict__ W2,
                     const float* __restrict__ b2, float* __restrict__ out)
{
    int idx = blockIdx.x * blockDim.x + threadIdx.x;
    if (idx >= N_GRAPHS * 16) return;
    int g = idx >> 4, c = idx & 15;
    float acc = b2[c];
    for (int kk = 0; kk < 64; ++kk)
        acc = fmaf(hidden[g * 64 + kk], W2[kk * 16 + c], acc);
    out[idx] = acc;
}

extern "C" void kernel_launch(void* const* d_in, const int* in_sizes, int n_in,
                              void* d_out, int out_size, void* d_ws, size_t ws_size,
                              hipStream_t stream)
{
    const float* x   = (const float*)d_in[0];
    const float* Wq0 = (const float*)d_in[1];  const float* bq0 = (const float*)d_in[2];
    const float* Wk0 = (const float*)d_in[3];  const float* bk0 = (const float*)d_in[4];
    const float* Wv0 = (const float*)d_in[5];  const float* bv0 = (const float*)d_in[6];
    const float* Ws0 = (const float*)d_in[7];  const float* bs0 = (const float*)d_in[8];
    const float* Wqs = (const float*)d_in[9];  const float* bqs = (const float*)d_in[10];
    const float* Wks = (const float*)d_in[11]; const float* bks = (const float*)d_in[12];
    const float* Wvs = (const float*)d_in[13]; const float* bvs = (const float*)d_in[14];
    const float* Wss = (const float*)d_in[15]; const float* bss = (const float*)d_in[16];
    const float* W1  = (const float*)d_in[17]; const float* b1  = (const float*)d_in[18];
    const float* W2  = (const float*)d_in[19]; const float* b2  = (const float*)d_in[20];
    const int*   ei  = (const int*)d_in[21];
    const int*   batch = (const int*)d_in[22];
    float* out = (float*)d_out;

    const int* src = ei;
    const int* dst = ei + N_EDGES;

    const size_t NH = (size_t)N_NODES * 64;
    float* q        = (float*)d_ws;
    float* hA       = q + NH;
    float* hB       = hA + NH;
    float* scores   = hB + NH;                      // CSR order
    float* csr_exp  = scores + N_EDGES;
    int2*  csr_sd   = (int2*)(csr_exp + N_EDGES);   // E int2 (8B aligned)
    unsigned short* kb = (unsigned short*)(csr_sd + N_EDGES);  // NH bf16
    unsigned short* vb = kb + NH;                              // NH bf16
    int*   row_start= (int*)(vb + NH);              // N_NODES+1
    int*   cursor   = row_start + N_NODES + 1;      // N_NODES
    int*   counts   = cursor + N_NODES;             // N_NODES
    int*   blockSums= counts + N_NODES;             // 512
    float* pooled   = (float*)(blockSums + 512);
    float* hidden   = pooled + N_GRAPHS * 64;

    struct LW { const float *Wq,*bq,*Wk,*bk,*Wv,*bv,*Ws,*bs; };
    LW lw[3] = {
        { Wq0, bq0, Wk0, bk0, Wv0, bv0, Ws0, bs0 },
        { Wqs, bqs, Wks, bks, Wvs, bvs, Wss, bss },
        { Wqs + 4096, bqs + 64, Wks + 4096, bks + 64, Wvs + 4096, bvs + 64, Wss + 4096, bss + 64 }
    };

    const int nodeBlocks   = (N_NODES + 255) / 256;
    const int edgeBlocks   = (N_EDGES + 255) / 256;
    const int edgeBlocks16 = (N_EDGES * 16 + 255) / 256;
    const int scanBlocks   = (N_NODES + 255) / 256;   // 391

    // ---- CSR build (once; edge_index constant across layers) ----
    zero_i<<<nodeBlocks, 256, 0, stream>>>(counts, N_NODES);
    count_deg<<<edgeBlocks, 256, 0, stream>>>(dst, counts, N_EDGES);
    scan1<<<scanBlocks, 256, 0, stream>>>(counts, counts, blockSums, N_NODES);
    scan2<<<1, 512, 0, stream>>>(blockSums, scanBlocks);
    scan3<<<(N_NODES + 256) / 256, 256, 0, stream>>>(counts, blockSums, row_start, cursor,
                                                     N_NODES, N_EDGES);
    csr_fill<<<edgeBlocks, 256, 0, stream>>>(src, dst, cursor, csr_sd, N_EDGES);

    // ---- 3 TransformerConv layers ----
    const dim3 gemmGrid(4, (N_NODES + 63) / 64);
    for (int L = 0; L < 3; ++L) {
        if (L == 0) {
            qkvs_gemm<IN_DIM><<<gemmGrid, 256, 0, stream>>>(x, N_NODES,
                lw[0].Wq, lw[0].bq, lw[0].Wk, lw[0].bk, lw[0].Wv, lw[0].bv, lw[0].Ws, lw[0].bs,
                q, kb, vb, hA);
        } else {
            const float* hin = (L == 1) ? hA : hB;
            float* hou       = (L == 1) ? hB : hA;
            qkvs_gemm<HID><<<gemmGrid, 256, 0, stream>>>(hin, N_NODES,
                lw[L].Wq, lw[L].bq, lw[L].Wk, lw[L].bk, lw[L].Wv, lw[L].bv, lw[L].Ws, lw[L].bs,
                q, kb, vb, hou);
        }
        float* hou = (L == 0) ? hA : ((L == 1) ? hB : hA);
        edge_scores<<<edgeBlocks16, 256, 0, stream>>>(q, kb, csr_sd, scores, N_EDGES);
        node_agg<<<(N_NODES + 3) / 4, 256, 0, stream>>>(vb, scores, csr_sd, row_start,
                                                        csr_exp, hou, N_NODES);
    }

    // ---- pool + MLP ----
    zero_f<<<(N_GRAPHS * 64 + 255) / 256, 256, 0, stream>>>(pooled, N_GRAPHS * 64);
    pool_kernel<<<(N_NODES + 127) / 128, 256, 0, stream>>>(hA, batch, pooled, N_NODES);
    mlp1<<<(N_GRAPHS * 64 + 255) / 256, 256, 0, stream>>>(pooled, W1, b1, hidden);
    mlp2<<<(N_GRAPHS * 16 + 255) / 256, 256, 0, stream>>>(hidden, W2, b2, out);
}

// Round 14
// 779.618 us; speedup vs baseline: 6.5931x; 1.0291x over previous
//
#include <hip/hip_runtime.h>
#include <hip/hip_bf16.h>

#define N_NODES 100000
#define N_EDGES 1600000
#define IN_DIM  128
#define HID     64
#define N_GRAPHS 500

// bf16 helpers (RNE pack, shift unpack)
__device__ inline unsigned short f2bf(float f) {
    unsigned u = __float_as_uint(f);
    u += 0x7FFFu + ((u >> 16) & 1u);
    return (unsigned short)(u >> 16);
}
__device__ inline float bf2f(unsigned short b) {
    return __uint_as_float(((unsigned)b) << 16);
}

// dot(q[node], k_row) where qreg = q[node][lane] (lane-distributed, wave-uniform node)
// and k_row is a 64-elem bf16 row local to this lane. 8 uint4 loads -> high MLP.
__device__ inline float dot64_q_bf16(float qreg, const unsigned short* __restrict__ krow) {
    const uint4* kp = (const uint4*)krow;
    uint4 kr[8];
    #pragma unroll
    for (int i = 0; i < 8; ++i) kr[i] = kp[i];
    float dot = 0.f;
    #pragma unroll
    for (int i = 0; i < 8; ++i) {
        #pragma unroll
        for (int c = 0; c < 4; ++c) {
            unsigned w = (&kr[i].x)[c];
            float qa = __shfl(qreg, i * 8 + c * 2);      // compile-time lane -> readlane
            float qb = __shfl(qreg, i * 8 + c * 2 + 1);
            dot = fmaf(qa, __uint_as_float(w << 16), dot);
            dot = fmaf(qb, __uint_as_float(w & 0xFFFF0000u), dot);
        }
    }
    return dot;
}

// ============ CSR build ============
__global__ void zero_i(int* p, int n) {
    int i = blockIdx.x * blockDim.x + threadIdx.x;
    if (i < n) p[i] = 0;
}

__global__ void count_deg(const int* __restrict__ dst, int* __restrict__ counts, int E) {
    int e = blockIdx.x * blockDim.x + threadIdx.x;
    if (e < E) atomicAdd(&counts[dst[e]], 1);
}

__global__ void scan1(const int* __restrict__ counts, int* __restrict__ pre,
                      int* __restrict__ blockSums, int n) {
    __shared__ int tmp[256];
    int tid = threadIdx.x;
    int i = blockIdx.x * 256 + tid;
    int v = (i < n) ? counts[i] : 0;
    tmp[tid] = v; __syncthreads();
    int acc = v;
    for (int off = 1; off < 256; off <<= 1) {
        int add = (tid >= off) ? tmp[tid - off] : 0;
        __syncthreads();
        acc += add; tmp[tid] = acc;
        __syncthreads();
    }
    if (i < n) pre[i] = acc - v;
    if (tid == 255) blockSums[blockIdx.x] = acc;
}

__global__ void scan2(int* blockSums, int nb) {
    __shared__ int tmp[512];
    int tid = threadIdx.x;
    int v = (tid < nb) ? blockSums[tid] : 0;
    tmp[tid] = v; __syncthreads();
    int acc = v;
    for (int off = 1; off < 512; off <<= 1) {
        int add = (tid >= off) ? tmp[tid - off] : 0;
        __syncthreads();
        acc += add; tmp[tid] = acc;
        __syncthreads();
    }
    if (tid < nb) blockSums[tid] = acc - v;
}

__global__ void scan3(const int* __restrict__ pre, const int* __restrict__ blockSums,
                      int* __restrict__ row_start, int* __restrict__ cursor, int n, int E) {
    int i = blockIdx.x * blockDim.x + threadIdx.x;
    if (i < n) {
        int r = pre[i] + blockSums[i >> 8];
        row_start[i] = r;
        cursor[i] = r;
    } else if (i == n) {
        row_start[n] = E;
    }
}

__global__ void csr_fill(const int* __restrict__ src, const int* __restrict__ dst,
                         int* __restrict__ cursor, int2* __restrict__ csr_sd, int E) {
    int e = blockIdx.x * blockDim.x + threadIdx.x;
    if (e >= E) return;
    int d = dst[e];
    int p = atomicAdd(&cursor[d], 1);
    csr_sd[p] = make_int2(src[e], d);
}

// ============ qkvs via tiled GEMM (k,v emitted as bf16; q,skip fp32) ============
template<int DIN>
__global__ __launch_bounds__(256) void qkvs_gemm(
    const float* __restrict__ x, int N,
    const float* __restrict__ Wq, const float* __restrict__ bq,
    const float* __restrict__ Wk, const float* __restrict__ bk,
    const float* __restrict__ Wv, const float* __restrict__ bv,
    const float* __restrict__ Ws, const float* __restrict__ bs,
    float* __restrict__ q, unsigned short* __restrict__ kb,
    unsigned short* __restrict__ vb, float* __restrict__ hout)
{
    constexpr int BM = 64, BK = 32;
    __shared__ float As[BK][BM + 1];
    __shared__ float Bs[BK][64];

    const int by = blockIdx.x;         // matrix id
    const float* W    = (by == 0) ? Wq : (by == 1) ? Wk : (by == 2) ? Wv : Ws;
    const float* bias = (by == 0) ? bq : (by == 1) ? bk : (by == 2) ? bv : bs;

    const int row0 = blockIdx.y * BM;
    const int tid  = threadIdx.x;
    const int tx   = (tid & 15) * 4;
    const int ty   = (tid >> 4) * 4;

    float acc[4][4] = {};

    for (int k0 = 0; k0 < DIN; k0 += BK) {
        #pragma unroll
        for (int h = 0; h < 2; ++h) {
            int idx = tid + h * 256;
            int r   = idx >> 3, c4 = idx & 7;
            int gr  = row0 + r;
            float4 val = (gr < N) ? *(const float4*)(x + (size_t)gr * DIN + k0 + c4 * 4)
                                  : make_float4(0.f, 0.f, 0.f, 0.f);
            int kk = c4 * 4;
            As[kk + 0][r] = val.x;
            As[kk + 1][r] = val.y;
            As[kk + 2][r] = val.z;
            As[kk + 3][r] = val.w;
        }
        #pragma unroll
        for (int h = 0; h < 2; ++h) {
            int kr = (tid >> 4) + h * 16;
            int n4 = (tid & 15) * 4;
            *(float4*)(&Bs[kr][n4]) = *(const float4*)(W + (size_t)(k0 + kr) * 64 + n4);
        }
        __syncthreads();

        #pragma unroll
        for (int kk = 0; kk < BK; ++kk) {
            float4 a = *(const float4*)(&As[kk][ty]);
            float4 b = *(const float4*)(&Bs[kk][tx]);
            acc[0][0] = fmaf(a.x, b.x, acc[0][0]);
            acc[0][1] = fmaf(a.x, b.y, acc[0][1]);
            acc[0][2] = fmaf(a.x, b.z, acc[0][2]);
            acc[0][3] = fmaf(a.x, b.w, acc[0][3]);
            acc[1][0] = fmaf(a.y, b.x, acc[1][0]);
            acc[1][1] = fmaf(a.y, b.y, acc[1][1]);
            acc[1][2] = fmaf(a.y, b.z, acc[1][2]);
            acc[1][3] = fmaf(a.y, b.w, acc[1][3]);
            acc[2][0] = fmaf(a.z, b.x, acc[2][0]);
            acc[2][1] = fmaf(a.z, b.y, acc[2][1]);
            acc[2][2] = fmaf(a.z, b.z, acc[2][2]);
            acc[2][3] = fmaf(a.z, b.w, acc[2][3]);
            acc[3][0] = fmaf(a.w, b.x, acc[3][0]);
            acc[3][1] = fmaf(a.w, b.y, acc[3][1]);
            acc[3][2] = fmaf(a.w, b.z, acc[3][2]);
            acc[3][3] = fmaf(a.w, b.w, acc[3][3]);
        }
        __syncthreads();
    }

    float4 bv4 = *(const float4*)(bias + tx);
    if (by == 1 || by == 2) {
        unsigned short* op = (by == 1) ? kb : vb;
        #pragma unroll
        for (int i = 0; i < 4; ++i) {
            int row = row0 + ty + i;
            if (row < N) {
                ushort4 pk;
                pk.x = f2bf(acc[i][0] + bv4.x);
                pk.y = f2bf(acc[i][1] + bv4.y);
                pk.z = f2bf(acc[i][2] + bv4.z);
                pk.w = f2bf(acc[i][3] + bv4.w);
                *(ushort4*)(op + (size_t)row * 64 + tx) = pk;
            }
        }
    } else {
        float* op = (by == 0) ? q : hout;
        #pragma unroll
        for (int i = 0; i < 4; ++i) {
            int row = row0 + ty + i;
            if (row < N) {
                float4 o = make_float4(acc[i][0] + bv4.x, acc[i][1] + bv4.y,
                                       acc[i][2] + bv4.z, acc[i][3] + bv4.w);
                *(float4*)(op + (size_t)row * 64 + tx) = o;
            }
        }
    }
}

// ============ fused scores + softmax + aggregation + skip + relu ============
// Wave per node. Fast path deg<=64: lane l owns edge start+l — computes its
// score in-register (no scores round trip), shfl softmax, 8-deep PV gather.
__global__ __launch_bounds__(256) void node_attn(
    const float* __restrict__ q, const unsigned short* __restrict__ kb,
    const unsigned short* __restrict__ vb,
    const int2* __restrict__ csr_sd, const int* __restrict__ row_start,
    float* __restrict__ csr_exp, float* __restrict__ hout, int N)
{
    int node = blockIdx.x * 4 + (threadIdx.x >> 6);
    int lane = threadIdx.x & 63;
    if (node >= N) return;
    int start = row_start[node], end = row_start[node + 1];
    int deg = end - start;
    size_t o = (size_t)node * 64 + lane;

    if (deg == 0) { hout[o] = fmaxf(hout[o], 0.f); return; }

    float qreg = q[o];   // q[node][lane], coalesced
    float acc = 0.f;

    if (deg <= 64) {
        int s_l = (lane < deg) ? csr_sd[start + lane].x : 0;
        float dot = dot64_q_bf16(qreg, kb + (size_t)s_l * 64);
        float sc = (lane < deg) ? dot * 0.125f : -__builtin_inff();

        float m = sc;
        #pragma unroll
        for (int off = 1; off < 64; off <<= 1) m = fmaxf(m, __shfl_xor(m, off));

        float ex = expf(sc - m);      // lanes >= deg: exp(-inf)=0
        float ssum = ex;
        #pragma unroll
        for (int off = 1; off < 64; off <<= 1) ssum += __shfl_xor(ssum, off);
        float alpha = ex * (1.f / (ssum + 1e-16f));

        int j = 0;
        for (; j + 8 <= deg; j += 8) {
            float a0 = __shfl(alpha, j),     a1 = __shfl(alpha, j + 1);
            float a2 = __shfl(alpha, j + 2), a3 = __shfl(alpha, j + 3);
            float a4 = __shfl(alpha, j + 4), a5 = __shfl(alpha, j + 5);
            float a6 = __shfl(alpha, j + 6), a7 = __shfl(alpha, j + 7);
            int   s0 = __shfl(s_l, j),       s1 = __shfl(s_l, j + 1);
            int   s2 = __shfl(s_l, j + 2),   s3 = __shfl(s_l, j + 3);
            int   s4 = __shfl(s_l, j + 4),   s5 = __shfl(s_l, j + 5);
            int   s6 = __shfl(s_l, j + 6),   s7 = __shfl(s_l, j + 7);
            float v0 = bf2f(vb[(size_t)s0 * 64 + lane]);
            float v1 = bf2f(vb[(size_t)s1 * 64 + lane]);
            float v2 = bf2f(vb[(size_t)s2 * 64 + lane]);
            float v3 = bf2f(vb[(size_t)s3 * 64 + lane]);
            float v4 = bf2f(vb[(size_t)s4 * 64 + lane]);
            float v5 = bf2f(vb[(size_t)s5 * 64 + lane]);
            float v6 = bf2f(vb[(size_t)s6 * 64 + lane]);
            float v7 = bf2f(vb[(size_t)s7 * 64 + lane]);
            acc = fmaf(a0, v0, acc); acc = fmaf(a1, v1, acc);
            acc = fmaf(a2, v2, acc); acc = fmaf(a3, v3, acc);
            acc = fmaf(a4, v4, acc); acc = fmaf(a5, v5, acc);
            acc = fmaf(a6, v6, acc); acc = fmaf(a7, v7, acc);
        }
        for (; j + 4 <= deg; j += 4) {
            float a0 = __shfl(alpha, j),     a1 = __shfl(alpha, j + 1);
            float a2 = __shfl(alpha, j + 2), a3 = __shfl(alpha, j + 3);
            int   s0 = __shfl(s_l, j),       s1 = __shfl(s_l, j + 1);
            int   s2 = __shfl(s_l, j + 2),   s3 = __shfl(s_l, j + 3);
            float v0 = bf2f(vb[(size_t)s0 * 64 + lane]);
            float v1 = bf2f(vb[(size_t)s1 * 64 + lane]);
            float v2 = bf2f(vb[(size_t)s2 * 64 + lane]);
            float v3 = bf2f(vb[(size_t)s3 * 64 + lane]);
            acc = fmaf(a0, v0, acc); acc = fmaf(a1, v1, acc);
            acc = fmaf(a2, v2, acc); acc = fmaf(a3, v3, acc);
        }
        for (; j < deg; ++j) {
            float a = __shfl(alpha, j);
            int   s = __shfl(s_l, j);
            acc = fmaf(a, bf2f(vb[(size_t)s * 64 + lane]), acc);
        }
    } else {
        // rare fallback: per-lane strided score computation through csr_exp
        float m = -__builtin_inff();
        for (int j = start + lane; j < end; j += 64) {
            int s = csr_sd[j].x;
            float sc = dot64_q_bf16(qreg, kb + (size_t)s * 64) * 0.125f;
            csr_exp[j] = sc;
            m = fmaxf(m, sc);
        }
        #pragma unroll
        for (int off = 1; off < 64; off <<= 1) m = fmaxf(m, __shfl_xor(m, off));

        float ssum = 0.f;
        for (int j = start + lane; j < end; j += 64) {
            float ex = expf(csr_exp[j] - m);
            csr_exp[j] = ex;
            ssum += ex;
        }
        #pragma unroll
        for (int off = 1; off < 64; off <<= 1) ssum += __shfl_xor(ssum, off);
        float inv = 1.f / (ssum + 1e-16f);

        for (int j = start; j < end; ++j) {
            int s   = csr_sd[j].x;
            float a = csr_exp[j] * inv;
            acc = fmaf(a, bf2f(vb[(size_t)s * 64 + lane]), acc);
        }
    }

    hout[o] = fmaxf(hout[o] + acc, 0.f);
}

// ============ pool + MLP ============
__global__ void zero_f(float* p, int n) {
    int i = blockIdx.x * blockDim.x + threadIdx.x;
    if (i < n) p[i] = 0.f;
}

__global__ void pool_kernel(const float* __restrict__ h, const int* __restrict__ batch,
                            float* __restrict__ pooled, int N)
{
    int col = threadIdx.x & 63;
    int rg  = threadIdx.x >> 6;
    int base = blockIdx.x * 128;
    int end  = base + 128; if (end > N) end = N;
    int gcur = -1; float acc = 0.f;
    for (int i = base + rg; i < end; i += 4) {
        int g = batch[i];
        if (g != gcur) {
            if (gcur >= 0) atomicAdd(&pooled[gcur * 64 + col], acc);
            gcur = g; acc = 0.f;
        }
        acc += h[(size_t)i * 64 + col];
    }
    if (gcur >= 0) atomicAdd(&pooled[gcur * 64 + col], acc);
}

__global__ void mlp1(const float* __restrict__ pooled, const float* __restrict__ W1,
                     const float* __restrict__ b1, float* __restrict__ hidden)
{
    int idx = blockIdx.x * blockDim.x + threadIdx.x;
    if (idx >= N_GRAPHS * 64) return;
    int g = idx >> 6, c = idx & 63;
    float acc = b1[c];
    for (int kk = 0; kk < 64; ++kk)
        acc = fmaf(pooled[g * 64 + kk], W1[kk * 64 + c], acc);
    hidden[idx] = fmaxf(acc, 0.f);
}

__global__ void mlp2(const float* __restrict__ hidden, const float* __restrict__ W2,
                     const float* __restrict__ b2, float* __restrict__ out)
{
    int idx = blockIdx.x * blockDim.x + threadIdx.x;
    if (idx >= N_GRAPHS * 16) return;
    int g = idx >> 4, c = idx & 15;
    float acc = b2[c];
    for (int kk = 0; kk < 64; ++kk)
        acc = fmaf(hidden[g * 64 + kk], W2[kk * 16 + c], acc);
    out[idx] = acc;
}

extern "C" void kernel_launch(void* const* d_in, const int* in_sizes, int n_in,
                              void* d_out, int out_size, void* d_ws, size_t ws_size,
                              hipStream_t stream)
{
    const float* x   = (const float*)d_in[0];
    const float* Wq0 = (const float*)d_in[1];  const float* bq0 = (const float*)d_in[2];
    const float* Wk0 = (const float*)d_in[3];  const float* bk0 = (const float*)d_in[4];
    const float* Wv0 = (const float*)d_in[5];  const float* bv0 = (const float*)d_in[6];
    const float* Ws0 = (const float*)d_in[7];  const float* bs0 = (const float*)d_in[8];
    const float* Wqs = (const float*)d_in[9];  const float* bqs = (const float*)d_in[10];
    const float* Wks = (const float*)d_in[11]; const float* bks = (const float*)d_in[12];
    const float* Wvs = (const float*)d_in[13]; const float* bvs = (const float*)d_in[14];
    const float* Wss = (const float*)d_in[15]; const float* bss = (const float*)d_in[16];
    const float* W1  = (const float*)d_in[17]; const float* b1  = (const float*)d_in[18];
    const float* W2  = (const float*)d_in[19]; const float* b2  = (const float*)d_in[20];
    const int*   ei  = (const int*)d_in[21];
    const int*   batch = (const int*)d_in[22];
    float* out = (float*)d_out;

    const int* src = ei;
    const int* dst = ei + N_EDGES;

    const size_t NH = (size_t)N_NODES * 64;
    float* q        = (float*)d_ws;
    float* hA       = q + NH;
    float* hB       = hA + NH;
    float* csr_exp  = hB + NH;                      // E floats (fallback only)
    int2*  csr_sd   = (int2*)(csr_exp + N_EDGES);   // E int2
    unsigned short* kb = (unsigned short*)(csr_sd + N_EDGES);  // NH bf16
    unsigned short* vb = kb + NH;                              // NH bf16
    int*   row_start= (int*)(vb + NH);              // N_NODES+1
    int*   cursor   = row_start + N_NODES + 1;      // N_NODES
    int*   counts   = cursor + N_NODES;             // N_NODES
    int*   blockSums= counts + N_NODES;             // 512
    float* pooled   = (float*)(blockSums + 512);
    float* hidden   = pooled + N_GRAPHS * 64;

    struct LW { const float *Wq,*bq,*Wk,*bk,*Wv,*bv,*Ws,*bs; };
    LW lw[3] = {
        { Wq0, bq0, Wk0, bk0, Wv0, bv0, Ws0, bs0 },
        { Wqs, bqs, Wks, bks, Wvs, bvs, Wss, bss },
        { Wqs + 4096, bqs + 64, Wks + 4096, bks + 64, Wvs + 4096, bvs + 64, Wss + 4096, bss + 64 }
    };

    const int nodeBlocks   = (N_NODES + 255) / 256;
    const int edgeBlocks   = (N_EDGES + 255) / 256;
    const int scanBlocks   = (N_NODES + 255) / 256;   // 391

    // ---- CSR build (once; edge_index constant across layers) ----
    zero_i<<<nodeBlocks, 256, 0, stream>>>(counts, N_NODES);
    count_deg<<<edgeBlocks, 256, 0, stream>>>(dst, counts, N_EDGES);
    scan1<<<scanBlocks, 256, 0, stream>>>(counts, counts, blockSums, N_NODES);
    scan2<<<1, 512, 0, stream>>>(blockSums, scanBlocks);
    scan3<<<(N_NODES + 256) / 256, 256, 0, stream>>>(counts, blockSums, row_start, cursor,
                                                     N_NODES, N_EDGES);
    csr_fill<<<edgeBlocks, 256, 0, stream>>>(src, dst, cursor, csr_sd, N_EDGES);

    // ---- 3 TransformerConv layers ----
    const dim3 gemmGrid(4, (N_NODES + 63) / 64);
    for (int L = 0; L < 3; ++L) {
        if (L == 0) {
            qkvs_gemm<IN_DIM><<<gemmGrid, 256, 0, stream>>>(x, N_NODES,
                lw[0].Wq, lw[0].bq, lw[0].Wk, lw[0].bk, lw[0].Wv, lw[0].bv, lw[0].Ws, lw[0].bs,
                q, kb, vb, hA);
        } else {
            const float* hin = (L == 1) ? hA : hB;
            float* hou       = (L == 1) ? hB : hA;
            qkvs_gemm<HID><<<gemmGrid, 256, 0, stream>>>(hin, N_NODES,
                lw[L].Wq, lw[L].bq, lw[L].Wk, lw[L].bk, lw[L].Wv, lw[L].bv, lw[L].Ws, lw[L].bs,
                q, kb, vb, hou);
        }
        float* hou = (L == 0) ? hA : ((L == 1) ? hB : hA);
        node_attn<<<(N_NODES + 3) / 4, 256, 0, stream>>>(q, kb, vb, csr_sd, row_start,
                                                         csr_exp, hou, N_NODES);
    }

    // ---- pool + MLP ----
    zero_f<<<(N_GRAPHS * 64 + 255) / 256, 256, 0, stream>>>(pooled, N_GRAPHS * 64);
    pool_kernel<<<(N_NODES + 127) / 128, 256, 0, stream>>>(hA, batch, pooled, N_NODES);
    mlp1<<<(N_GRAPHS * 64 + 255) / 256, 256, 0, stream>>>(pooled, W1, b1, hidden);
    mlp2<<<(N_GRAPHS * 16 + 255) / 256, 256, 0, stream>>>(hidden, W2, b2, out);
}

// Round 15
// 682.931 us; speedup vs baseline: 7.5266x; 1.1416x over previous
//
#include <hip/hip_runtime.h>
#include <hip/hip_bf16.h>

#define N_NODES 100000
#define N_EDGES 1600000
#define IN_DIM  128
#define HID     64
#define N_GRAPHS 500

// bf16 helpers (RNE pack, shift unpack)
__device__ inline unsigned short f2bf(float f) {
    unsigned u = __float_as_uint(f);
    u += 0x7FFFu + ((u >> 16) & 1u);
    return (unsigned short)(u >> 16);
}
__device__ inline float bf2f(unsigned short b) {
    return __uint_as_float(((unsigned)b) << 16);
}

// dot(q[node], k_row): qreg = q[node][lane] (lane-distributed, wave-uniform node),
// k_row = 64-elem bf16 row local to this lane. 8 uint4 loads -> high MLP.
__device__ inline float dot64_q_bf16(float qreg, const unsigned short* __restrict__ krow) {
    const uint4* kp = (const uint4*)krow;
    uint4 kr[8];
    #pragma unroll
    for (int i = 0; i < 8; ++i) kr[i] = kp[i];
    float dot = 0.f;
    #pragma unroll
    for (int i = 0; i < 8; ++i) {
        #pragma unroll
        for (int c = 0; c < 4; ++c) {
            unsigned w = (&kr[i].x)[c];
            float qa = __shfl(qreg, i * 8 + c * 2);      // compile-time lane -> readlane
            float qb = __shfl(qreg, i * 8 + c * 2 + 1);
            dot = fmaf(qa, __uint_as_float(w << 16), dot);
            dot = fmaf(qb, __uint_as_float(w & 0xFFFF0000u), dot);
        }
    }
    return dot;
}

// ============ CSR build ============
__global__ void zero_i(int* p, int n) {
    int i = blockIdx.x * blockDim.x + threadIdx.x;
    if (i < n) p[i] = 0;
}

// counts + per-edge rank in one pass (rank store is coalesced by e)
__global__ void count_rank(const int* __restrict__ dst, int* __restrict__ counts,
                           int* __restrict__ rank, int E) {
    int e = blockIdx.x * blockDim.x + threadIdx.x;
    if (e < E) rank[e] = atomicAdd(&counts[dst[e]], 1);
}

__global__ void scan1(const int* __restrict__ counts, int* __restrict__ pre,
                      int* __restrict__ blockSums, int n) {
    __shared__ int tmp[256];
    int tid = threadIdx.x;
    int i = blockIdx.x * 256 + tid;
    int v = (i < n) ? counts[i] : 0;
    tmp[tid] = v; __syncthreads();
    int acc = v;
    for (int off = 1; off < 256; off <<= 1) {
        int add = (tid >= off) ? tmp[tid - off] : 0;
        __syncthreads();
        acc += add; tmp[tid] = acc;
        __syncthreads();
    }
    if (i < n) pre[i] = acc - v;
    if (tid == 255) blockSums[blockIdx.x] = acc;
}

__global__ void scan2(int* blockSums, int nb) {
    __shared__ int tmp[512];
    int tid = threadIdx.x;
    int v = (tid < nb) ? blockSums[tid] : 0;
    tmp[tid] = v; __syncthreads();
    int acc = v;
    for (int off = 1; off < 512; off <<= 1) {
        int add = (tid >= off) ? tmp[tid - off] : 0;
        __syncthreads();
        acc += add; tmp[tid] = acc;
        __syncthreads();
    }
    if (tid < nb) blockSums[tid] = acc - v;
}

__global__ void scan3(const int* __restrict__ pre, const int* __restrict__ blockSums,
                      int* __restrict__ row_start, int n, int E) {
    int i = blockIdx.x * blockDim.x + threadIdx.x;
    if (i < n) {
        row_start[i] = pre[i] + blockSums[i >> 8];
    } else if (i == n) {
        row_start[n] = E;
    }
}

// atomic-free scatter: csr_src[row_start[dst] + rank] = src  (4B/edge, dst not stored)
__global__ void csr_scatter(const int* __restrict__ src, const int* __restrict__ dst,
                            const int* __restrict__ rank, const int* __restrict__ row_start,
                            int* __restrict__ csr_src, int E) {
    int e = blockIdx.x * blockDim.x + threadIdx.x;
    if (e >= E) return;
    csr_src[row_start[dst[e]] + rank[e]] = src[e];
}

// ============ qkvs via tiled GEMM (k,v emitted as bf16; q,skip fp32) ============
template<int DIN>
__global__ __launch_bounds__(256) void qkvs_gemm(
    const float* __restrict__ x, int N,
    const float* __restrict__ Wq, const float* __restrict__ bq,
    const float* __restrict__ Wk, const float* __restrict__ bk,
    const float* __restrict__ Wv, const float* __restrict__ bv,
    const float* __restrict__ Ws, const float* __restrict__ bs,
    float* __restrict__ q, unsigned short* __restrict__ kb,
    unsigned short* __restrict__ vb, float* __restrict__ hout)
{
    constexpr int BM = 64, BK = 32;
    __shared__ float As[BK][BM + 1];
    __shared__ float Bs[BK][64];

    const int by = blockIdx.x;         // matrix id
    const float* W    = (by == 0) ? Wq : (by == 1) ? Wk : (by == 2) ? Wv : Ws;
    const float* bias = (by == 0) ? bq : (by == 1) ? bk : (by == 2) ? bv : bs;

    const int row0 = blockIdx.y * BM;
    const int tid  = threadIdx.x;
    const int tx   = (tid & 15) * 4;
    const int ty   = (tid >> 4) * 4;

    float acc[4][4] = {};

    for (int k0 = 0; k0 < DIN; k0 += BK) {
        #pragma unroll
        for (int h = 0; h < 2; ++h) {
            int idx = tid + h * 256;
            int r   = idx >> 3, c4 = idx & 7;
            int gr  = row0 + r;
            float4 val = (gr < N) ? *(const float4*)(x + (size_t)gr * DIN + k0 + c4 * 4)
                                  : make_float4(0.f, 0.f, 0.f, 0.f);
            int kk = c4 * 4;
            As[kk + 0][r] = val.x;
            As[kk + 1][r] = val.y;
            As[kk + 2][r] = val.z;
            As[kk + 3][r] = val.w;
        }
        #pragma unroll
        for (int h = 0; h < 2; ++h) {
            int kr = (tid >> 4) + h * 16;
            int n4 = (tid & 15) * 4;
            *(float4*)(&Bs[kr][n4]) = *(const float4*)(W + (size_t)(k0 + kr) * 64 + n4);
        }
        __syncthreads();

        #pragma unroll
        for (int kk = 0; kk < BK; ++kk) {
            float4 a = *(const float4*)(&As[kk][ty]);
            float4 b = *(const float4*)(&Bs[kk][tx]);
            acc[0][0] = fmaf(a.x, b.x, acc[0][0]);
            acc[0][1] = fmaf(a.x, b.y, acc[0][1]);
            acc[0][2] = fmaf(a.x, b.z, acc[0][2]);
            acc[0][3] = fmaf(a.x, b.w, acc[0][3]);
            acc[1][0] = fmaf(a.y, b.x, acc[1][0]);
            acc[1][1] = fmaf(a.y, b.y, acc[1][1]);
            acc[1][2] = fmaf(a.y, b.z, acc[1][2]);
            acc[1][3] = fmaf(a.y, b.w, acc[1][3]);
            acc[2][0] = fmaf(a.z, b.x, acc[2][0]);
            acc[2][1] = fmaf(a.z, b.y, acc[2][1]);
            acc[2][2] = fmaf(a.z, b.z, acc[2][2]);
            acc[2][3] = fmaf(a.z, b.w, acc[2][3]);
            acc[3][0] = fmaf(a.w, b.x, acc[3][0]);
            acc[3][1] = fmaf(a.w, b.y, acc[3][1]);
            acc[3][2] = fmaf(a.w, b.z, acc[3][2]);
            acc[3][3] = fmaf(a.w, b.w, acc[3][3]);
        }
        __syncthreads();
    }

    float4 bv4 = *(const float4*)(bias + tx);
    if (by == 1 || by == 2) {
        unsigned short* op = (by == 1) ? kb : vb;
        #pragma unroll
        for (int i = 0; i < 4; ++i) {
            int row = row0 + ty + i;
            if (row < N) {
                ushort4 pk;
                pk.x = f2bf(acc[i][0] + bv4.x);
                pk.y = f2bf(acc[i][1] + bv4.y);
                pk.z = f2bf(acc[i][2] + bv4.z);
                pk.w = f2bf(acc[i][3] + bv4.w);
                *(ushort4*)(op + (size_t)row * 64 + tx) = pk;
            }
        }
    } else {
        float* op = (by == 0) ? q : hout;
        #pragma unroll
        for (int i = 0; i < 4; ++i) {
            int row = row0 + ty + i;
            if (row < N) {
                float4 o = make_float4(acc[i][0] + bv4.x, acc[i][1] + bv4.y,
                                       acc[i][2] + bv4.z, acc[i][3] + bv4.w);
                *(float4*)(op + (size_t)row * 64 + tx) = o;
            }
        }
    }
}

// ============ fused scores + softmax + aggregation + skip + relu ============
__global__ __launch_bounds__(256) void node_attn(
    const float* __restrict__ q, const unsigned short* __restrict__ kb,
    const unsigned short* __restrict__ vb,
    const int* __restrict__ csr_src, const int* __restrict__ row_start,
    float* __restrict__ csr_exp, float* __restrict__ hout, int N)
{
    int node = blockIdx.x * 4 + (threadIdx.x >> 6);
    int lane = threadIdx.x & 63;
    if (node >= N) return;
    int start = row_start[node], end = row_start[node + 1];
    int deg = end - start;
    size_t o = (size_t)node * 64 + lane;

    if (deg == 0) { hout[o] = fmaxf(hout[o], 0.f); return; }

    float qreg = q[o];   // q[node][lane], coalesced
    float acc = 0.f;

    if (deg <= 64) {
        int s_l = (lane < deg) ? csr_src[start + lane] : 0;
        float dot = dot64_q_bf16(qreg, kb + (size_t)s_l * 64);
        float sc = (lane < deg) ? dot * 0.125f : -__builtin_inff();

        float m = sc;
        #pragma unroll
        for (int off = 1; off < 64; off <<= 1) m = fmaxf(m, __shfl_xor(m, off));

        float ex = expf(sc - m);      // lanes >= deg: exp(-inf)=0
        float ssum = ex;
        #pragma unroll
        for (int off = 1; off < 64; off <<= 1) ssum += __shfl_xor(ssum, off);
        float alpha = ex * (1.f / (ssum + 1e-16f));

        int j = 0;
        for (; j + 16 <= deg; j += 16) {
            float a[16]; int s[16];
            #pragma unroll
            for (int t = 0; t < 16; ++t) {
                a[t] = __shfl(alpha, j + t);
                s[t] = __shfl(s_l, j + t);
            }
            float vv[16];
            #pragma unroll
            for (int t = 0; t < 16; ++t) vv[t] = bf2f(vb[(size_t)s[t] * 64 + lane]);
            #pragma unroll
            for (int t = 0; t < 16; ++t) acc = fmaf(a[t], vv[t], acc);
        }
        for (; j + 8 <= deg; j += 8) {
            float a[8]; int s[8];
            #pragma unroll
            for (int t = 0; t < 8; ++t) {
                a[t] = __shfl(alpha, j + t);
                s[t] = __shfl(s_l, j + t);
            }
            float vv[8];
            #pragma unroll
            for (int t = 0; t < 8; ++t) vv[t] = bf2f(vb[(size_t)s[t] * 64 + lane]);
            #pragma unroll
            for (int t = 0; t < 8; ++t) acc = fmaf(a[t], vv[t], acc);
        }
        for (; j + 4 <= deg; j += 4) {
            float a[4]; int s[4];
            #pragma unroll
            for (int t = 0; t < 4; ++t) {
                a[t] = __shfl(alpha, j + t);
                s[t] = __shfl(s_l, j + t);
            }
            float vv[4];
            #pragma unroll
            for (int t = 0; t < 4; ++t) vv[t] = bf2f(vb[(size_t)s[t] * 64 + lane]);
            #pragma unroll
            for (int t = 0; t < 4; ++t) acc = fmaf(a[t], vv[t], acc);
        }
        for (; j < deg; ++j) {
            float a = __shfl(alpha, j);
            int   s = __shfl(s_l, j);
            acc = fmaf(a, bf2f(vb[(size_t)s * 64 + lane]), acc);
        }
    } else {
        // rare fallback: per-lane strided score computation through csr_exp
        float m = -__builtin_inff();
        for (int j = start + lane; j < end; j += 64) {
            int s = csr_src[j];
            float sc = dot64_q_bf16(qreg, kb + (size_t)s * 64) * 0.125f;
            csr_exp[j] = sc;
            m = fmaxf(m, sc);
        }
        #pragma unroll
        for (int off = 1; off < 64; off <<= 1) m = fmaxf(m, __shfl_xor(m, off));

        float ssum = 0.f;
        for (int j = start + lane; j < end; j += 64) {
            float ex = expf(csr_exp[j] - m);
            csr_exp[j] = ex;
            ssum += ex;
        }
        #pragma unroll
        for (int off = 1; off < 64; off <<= 1) ssum += __shfl_xor(ssum, off);
        float inv = 1.f / (ssum + 1e-16f);

        for (int j = start; j < end; ++j) {
            int s   = csr_src[j];
            float a = csr_exp[j] * inv;
            acc = fmaf(a, bf2f(vb[(size_t)s * 64 + lane]), acc);
        }
    }

    hout[o] = fmaxf(hout[o] + acc, 0.f);
}

// ============ pool + MLP ============
__global__ void zero_f(float* p, int n) {
    int i = blockIdx.x * blockDim.x + threadIdx.x;
    if (i < n) p[i] = 0.f;
}

__global__ void pool_kernel(const float* __restrict__ h, const int* __restrict__ batch,
                            float* __restrict__ pooled, int N)
{
    int col = threadIdx.x & 63;
    int rg  = threadIdx.x >> 6;
    int base = blockIdx.x * 128;
    int end  = base + 128; if (end > N) end = N;
    int gcur = -1; float acc = 0.f;
    for (int i = base + rg; i < end; i += 4) {
        int g = batch[i];
        if (g != gcur) {
            if (gcur >= 0) atomicAdd(&pooled[gcur * 64 + col], acc);
            gcur = g; acc = 0.f;
        }
        acc += h[(size_t)i * 64 + col];
    }
    if (gcur >= 0) atomicAdd(&pooled[gcur * 64 + col], acc);
}

__global__ void mlp1(const float* __restrict__ pooled, const float* __restrict__ W1,
                     const float* __restrict__ b1, float* __restrict__ hidden)
{
    int idx = blockIdx.x * blockDim.x + threadIdx.x;
    if (idx >= N_GRAPHS * 64) return;
    int g = idx >> 6, c = idx & 63;
    float acc = b1[c];
    for (int kk = 0; kk < 64; ++kk)
        acc = fmaf(pooled[g * 64 + kk], W1[kk * 64 + c], acc);
    hidden[idx] = fmaxf(acc, 0.f);
}

__global__ void mlp2(const float* __restrict__ hidden, const float* __restrict__ W2,
                     const float* __restrict__ b2, float* __restrict__ out)
{
    int idx = blockIdx.x * blockDim.x + threadIdx.x;
    if (idx >= N_GRAPHS * 16) return;
    int g = idx >> 4, c = idx & 15;
    float acc = b2[c];
    for (int kk = 0; kk < 64; ++kk)
        acc = fmaf(hidden[g * 64 + kk], W2[kk * 16 + c], acc);
    out[idx] = acc;
}

extern "C" void kernel_launch(void* const* d_in, const int* in_sizes, int n_in,
                              void* d_out, int out_size, void* d_ws, size_t ws_size,
                              hipStream_t stream)
{
    const float* x   = (const float*)d_in[0];
    const float* Wq0 = (const float*)d_in[1];  const float* bq0 = (const float*)d_in[2];
    const float* Wk0 = (const float*)d_in[3];  const float* bk0 = (const float*)d_in[4];
    const float* Wv0 = (const float*)d_in[5];  const float* bv0 = (const float*)d_in[6];
    const float* Ws0 = (const float*)d_in[7];  const float* bs0 = (const float*)d_in[8];
    const float* Wqs = (const float*)d_in[9];  const float* bqs = (const float*)d_in[10];
    const float* Wks = (const float*)d_in[11]; const float* bks = (const float*)d_in[12];
    const float* Wvs = (const float*)d_in[13]; const float* bvs = (const float*)d_in[14];
    const float* Wss = (const float*)d_in[15]; const float* bss = (const float*)d_in[16];
    const float* W1  = (const float*)d_in[17]; const float* b1  = (const float*)d_in[18];
    const float* W2  = (const float*)d_in[19]; const float* b2  = (const float*)d_in[20];
    const int*   ei  = (const int*)d_in[21];
    const int*   batch = (const int*)d_in[22];
    float* out = (float*)d_out;

    const int* src = ei;
    const int* dst = ei + N_EDGES;

    const size_t NH = (size_t)N_NODES * 64;
    float* q        = (float*)d_ws;
    float* hA       = q + NH;
    float* hB       = hA + NH;
    float* csr_exp  = hB + NH;                      // E floats (fallback only)
    int*   csr_src  = (int*)(csr_exp + N_EDGES);    // E ints
    int*   rank     = csr_src + N_EDGES;            // E ints
    unsigned short* kb = (unsigned short*)(rank + N_EDGES);  // NH bf16
    unsigned short* vb = kb + NH;                            // NH bf16
    int*   row_start= (int*)(vb + NH);              // N_NODES+1
    int*   counts   = row_start + N_NODES + 1;      // N_NODES
    int*   blockSums= counts + N_NODES;             // 512
    float* pooled   = (float*)(blockSums + 512);
    float* hidden   = pooled + N_GRAPHS * 64;

    struct LW { const float *Wq,*bq,*Wk,*bk,*Wv,*bv,*Ws,*bs; };
    LW lw[3] = {
        { Wq0, bq0, Wk0, bk0, Wv0, bv0, Ws0, bs0 },
        { Wqs, bqs, Wks, bks, Wvs, bvs, Wss, bss },
        { Wqs + 4096, bqs + 64, Wks + 4096, bks + 64, Wvs + 4096, bvs + 64, Wss + 4096, bss + 64 }
    };

    const int nodeBlocks   = (N_NODES + 255) / 256;
    const int edgeBlocks   = (N_EDGES + 255) / 256;
    const int scanBlocks   = (N_NODES + 255) / 256;   // 391

    // ---- CSR build (atomic rank pass + scan + atomic-free scatter) ----
    zero_i<<<nodeBlocks, 256, 0, stream>>>(counts, N_NODES);
    count_rank<<<edgeBlocks, 256, 0, stream>>>(dst, counts, rank, N_EDGES);
    scan1<<<scanBlocks, 256, 0, stream>>>(counts, counts, blockSums, N_NODES);
    scan2<<<1, 512, 0, stream>>>(blockSums, scanBlocks);
    scan3<<<(N_NODES + 256) / 256, 256, 0, stream>>>(counts, blockSums, row_start,
                                                     N_NODES, N_EDGES);
    csr_scatter<<<edgeBlocks, 256, 0, stream>>>(src, dst, rank, row_start, csr_src, N_EDGES);

    // ---- 3 TransformerConv layers ----
    const dim3 gemmGrid(4, (N_NODES + 63) / 64);
    for (int L = 0; L < 3; ++L) {
        if (L == 0) {
            qkvs_gemm<IN_DIM><<<gemmGrid, 256, 0, stream>>>(x, N_NODES,
                lw[0].Wq, lw[0].bq, lw[0].Wk, lw[0].bk, lw[0].Wv, lw[0].bv, lw[0].Ws, lw[0].bs,
                q, kb, vb, hA);
        } else {
            const float* hin = (L == 1) ? hA : hB;
            float* hou       = (L == 1) ? hB : hA;
            qkvs_gemm<HID><<<gemmGrid, 256, 0, stream>>>(hin, N_NODES,
                lw[L].Wq, lw[L].bq, lw[L].Wk, lw[L].bk, lw[L].Wv, lw[L].bv, lw[L].Ws, lw[L].bs,
                q, kb, vb, hou);
        }
        float* hou = (L == 0) ? hA : ((L == 1) ? hB : hA);
        node_attn<<<(N_NODES + 3) / 4, 256, 0, stream>>>(q, kb, vb, csr_src, row_start,
                                                         csr_exp, hou, N_NODES);
    }

    // ---- pool + MLP ----
    zero_f<<<(N_GRAPHS * 64 + 255) / 256, 256, 0, stream>>>(pooled, N_GRAPHS * 64);
    pool_kernel<<<(N_NODES + 127) / 128, 256, 0, stream>>>(hA, batch, pooled, N_NODES);
    mlp1<<<(N_GRAPHS * 64 + 255) / 256, 256, 0, stream>>>(pooled, W1, b1, hidden);
    mlp2<<<(N_GRAPHS * 16 + 255) / 256, 256, 0, stream>>>(hidden, W2, b2, out);
}